// Round 2
// baseline (3412.546 us; speedup 1.0000x reference)
//
#include <hip/hip_runtime.h>
#include <math.h>

#define D 64
#define NEG 0.2f
#define WPB 4              // waves per block
#define BLK (WPB * 64)
#define DPB 128            // dst nodes per bucket
#define MAXNB 1024         // max buckets (N <= 131072)

__device__ __forceinline__ float lrelu(float v) { return v > 0.f ? v : NEG * v; }

__device__ __forceinline__ const int* edge_ptr(const int* e0, const int* e1,
                                               const int* e2, const int* e3, int r)
{
    return (r == 0) ? e0 : (r == 1) ? e1 : (r == 2) ? e2 : e3;
}

// ---------------- bucketed CSR build ----------------

// bucket histogram (LDS-staged), reads dst row only
__global__ __launch_bounds__(256) void k_bcount(
    const int* __restrict__ e0, const int* __restrict__ e1,
    const int* __restrict__ e2, const int* __restrict__ e3,
    int* __restrict__ bcnt, int E, int NB)
{
    int r = blockIdx.y;
    const int* dst = edge_ptr(e0, e1, e2, e3, r) + E;
    __shared__ int hist[MAXNB];
    for (int i = threadIdx.x; i < NB; i += 256) hist[i] = 0;
    __syncthreads();
    int base = blockIdx.x * 4096;
    int end = base + 4096 < E ? base + 4096 : E;
    for (int i = base + threadIdx.x; i < end; i += 256)
        atomicAdd(&hist[dst[i] >> 7], 1);
    __syncthreads();
    for (int i = threadIdx.x; i < NB; i += 256)
        if (hist[i]) atomicAdd(&bcnt[r * NB + i], hist[i]);
}

// exclusive scan of bucket counts -> boff (NB+1 entries), init bucket cursors
__global__ __launch_bounds__(1024) void k_bscan(
    const int* __restrict__ bcnt, int* __restrict__ boff,
    int* __restrict__ bcur, int* __restrict__ prefix, int E, int N, int NB)
{
    int r = blockIdx.y;
    __shared__ int sh[1024];
    int t = threadIdx.x;
    int v = (t < NB) ? bcnt[r * NB + t] : 0;
    sh[t] = v;
    __syncthreads();
    for (int off = 1; off < 1024; off <<= 1) {
        int add = (t >= off) ? sh[t - off] : 0;
        __syncthreads();
        sh[t] += add;
        __syncthreads();
    }
    if (t < NB) {
        int excl = sh[t] - v;
        boff[r * (NB + 1) + t] = excl;
        bcur[r * NB + t] = excl;
    }
    if (t == 0) {
        boff[r * (NB + 1) + NB] = E;
        prefix[(size_t)r * (N + 1) + N] = E;
    }
}

// scatter packed (src<<7 | dst&127) into per-bucket staging regions
__global__ __launch_bounds__(256) void k_bscat(
    const int* __restrict__ e0, const int* __restrict__ e1,
    const int* __restrict__ e2, const int* __restrict__ e3,
    int* __restrict__ bcur, unsigned* __restrict__ staging, int E, int NB)
{
    int r = blockIdx.y;
    const int* ep = edge_ptr(e0, e1, e2, e3, r);
    int i = blockIdx.x * 256 + threadIdx.x;
    if (i < E) {
        int s = ep[i];
        int d = ep[E + i];
        int b = d >> 7;
        int pos = atomicAdd(&bcur[r * NB + b], 1);
        staging[(size_t)r * E + pos] = ((unsigned)s << 7) | (unsigned)(d & 127);
    }
}

// one block per (bucket, relation): local per-dst count+scan, write prefix, place srcs
__global__ __launch_bounds__(256) void k_place(
    const unsigned* __restrict__ staging, const int* __restrict__ boff,
    int* __restrict__ prefix, int* __restrict__ srcs, int N, int E, int NB)
{
    int r = blockIdx.y;
    int b = blockIdx.x;
    int t = threadIdx.x;
    __shared__ int lcount[DPB];
    __shared__ int ls[DPB];
    __shared__ int lcur[DPB];
    int gbase = boff[r * (NB + 1) + b];
    int bcnt = boff[r * (NB + 1) + b + 1] - gbase;
    if (t < DPB) lcount[t] = 0;
    __syncthreads();
    const unsigned* st = staging + (size_t)r * E + gbase;
    for (int i = t; i < bcnt; i += 256)
        atomicAdd(&lcount[st[i] & 127], 1);
    __syncthreads();
    if (t < DPB) ls[t] = lcount[t];
    __syncthreads();
    for (int off = 1; off < DPB; off <<= 1) {
        int add = (t < DPB && t >= off) ? ls[t - off] : 0;
        __syncthreads();
        if (t < DPB) ls[t] += add;
        __syncthreads();
    }
    int lo = b * DPB;
    if (t < DPB) {
        int excl = ls[t] - lcount[t];
        lcur[t] = excl;
        int d = lo + t;
        if (d < N) prefix[(size_t)r * (N + 1) + d] = gbase + excl;
    }
    __syncthreads();
    for (int i = t; i < bcnt; i += 256) {
        unsigned v = st[i];
        int pos = atomicAdd(&lcur[v & 127], 1);
        srcs[(size_t)r * E + gbase + pos] = (int)(v >> 7);
    }
}

// ---------------- per-layer compute ----------------

// h = x @ W ; a_src = h . att_s ; a_dst = h . att_d   (one wave per node)
__global__ __launch_bounds__(BLK) void k_gemm_h(
    const float* __restrict__ x, const float* __restrict__ W,
    const float* __restrict__ att_s, const float* __restrict__ att_d,
    float* __restrict__ h, float* __restrict__ a_s, float* __restrict__ a_d, int N)
{
    int lane = threadIdx.x & 63;
    int n = blockIdx.x * WPB + (threadIdx.x >> 6);
    if (n >= N) return;
    float xv = x[(size_t)n * D + lane];
    float acc = 0.f;
#pragma unroll
    for (int k = 0; k < D; k++) acc = fmaf(__shfl(xv, k), W[k * D + lane], acc);
    h[(size_t)n * D + lane] = acc;
    float ps = acc * att_s[lane];
    float pd = acc * att_d[lane];
#pragma unroll
    for (int off = 32; off; off >>= 1) {
        ps += __shfl_xor(ps, off);
        pd += __shfl_xor(pd, off);
    }
    if (lane == 0) { a_s[n] = ps; a_d[n] = pd; }
}

// hidden_pre[n,c] = b1[c] + sum_k x[n,k] * W1[k*64+c]    (x-part of MLP1)
__global__ __launch_bounds__(BLK) void k_mlp1x(
    const float* __restrict__ x, const float* __restrict__ W1,
    const float* __restrict__ b1, float* __restrict__ hp, int N)
{
    int lane = threadIdx.x & 63;
    int n = blockIdx.x * WPB + (threadIdx.x >> 6);
    if (n >= N) return;
    float xv = x[(size_t)n * D + lane];
    float acc = b1[lane];
#pragma unroll
    for (int k = 0; k < D; k++) acc = fmaf(__shfl(xv, k), W1[k * D + lane], acc);
    hp[(size_t)n * D + lane] = acc;
}

// GAT aggregation: single-pass online softmax over CSR + fused MLP1 slice.
// One wave per dst node; lane = feature dim.
__global__ __launch_bounds__(BLK) void k_agg(
    const float* __restrict__ h, const float* __restrict__ a_src,
    const float* __restrict__ a_dst, const int* __restrict__ starts,
    const int* __restrict__ srcs, const float* __restrict__ bias,
    const float* __restrict__ W1r, float* __restrict__ hp, int N)
{
    int lane = threadIdx.x & 63;
    int d = blockIdx.x * WPB + (threadIdx.x >> 6);
    if (d >= N) return;

    int base = starts[d];
    int cnt = starts[d + 1] - base;
    float ad = a_dst[d];

    // self-loop initializes the online-softmax state
    float m = lrelu(a_src[d] + ad);
    float z = 1.f;                                  // exp(self - m) = 1
    float acc = h[(size_t)d * D + lane];

    for (int j0 = 0; j0 < cnt; j0 += 64) {
        int jj = j0 + lane;
        bool valid = jj < cnt;
        int s = valid ? srcs[base + jj] : 0;
        float a = valid ? lrelu(a_src[s] + ad) : -1e30f;
        // chunk max
        float cm = a;
#pragma unroll
        for (int off = 32; off; off >>= 1) cm = fmaxf(cm, __shfl_xor(cm, off));
        if (cm > m) {
            float sc = __expf(m - cm);
            z *= sc;
            acc *= sc;
            m = cm;
        }
        float e = __expf(a - m);                    // underflows to 0 for invalid lanes
        int lim = (cnt - j0) < 64 ? (cnt - j0) : 64;
        for (int t = 0; t < lim; t++) {
            float et = __shfl(e, t);
            int st = __shfl(s, t);
            z += et;
            acc = fmaf(et, h[(size_t)st * D + lane], acc);
        }
    }

    float g = acc / z + bias[lane];   // GAT output feature `lane` for node d

    // fused MLP1 slice: hp[d,c] += sum_k g_k * W1r[k*64+c]
    float hpacc = 0.f;
#pragma unroll
    for (int k = 0; k < D; k++) hpacc = fmaf(__shfl(g, k), W1r[k * D + lane], hpacc);
    hp[(size_t)d * D + lane] += hpacc;
}

// x_out[n,c] = b2[c] + sum_k tanh(hp[n,k]) * W2[k*64+c]
__global__ __launch_bounds__(BLK) void k_mlp2(
    const float* __restrict__ hp, const float* __restrict__ W2,
    const float* __restrict__ b2, float* __restrict__ xout, int N)
{
    int lane = threadIdx.x & 63;
    int n = blockIdx.x * WPB + (threadIdx.x >> 6);
    if (n >= N) return;
    float hv = tanhf(hp[(size_t)n * D + lane]);
    float acc = b2[lane];
#pragma unroll
    for (int k = 0; k < D; k++) acc = fmaf(__shfl(hv, k), W2[k * D + lane], acc);
    xout[(size_t)n * D + lane] = acc;
}

// ---------------- launch ----------------

extern "C" void kernel_launch(void* const* d_in, const int* in_sizes, int n_in,
                              void* d_out, int out_size, void* d_ws, size_t ws_size,
                              hipStream_t stream)
{
    const float* x    = (const float*)d_in[0];
    const int*   e0   = (const int*)d_in[1];
    const int*   e1   = (const int*)d_in[2];
    const int*   e2   = (const int*)d_in[3];
    const int*   e3   = (const int*)d_in[4];
    const float* gatW = (const float*)d_in[5];   // (2,4,64,64)
    const float* atS  = (const float*)d_in[6];   // (2,4,64)
    const float* atD  = (const float*)d_in[7];
    const float* gatB = (const float*)d_in[8];
    const float* W1   = (const float*)d_in[9];   // (2,320,64)
    const float* b1   = (const float*)d_in[10];  // (2,64)
    const float* W2   = (const float*)d_in[11];  // (2,64,64)
    const float* b2   = (const float*)d_in[12];  // (2,64)
    float* out = (float*)d_out;

    const int N = in_sizes[0] / D;
    const int E = in_sizes[1] / 2;
    const int NB = (N + DPB - 1) / DPB;          // buckets per relation

    // workspace layout; staging (CSR-build only) aliases h (layer-compute only)
    size_t off = 0;
    auto alloc = [&](size_t bytes) { size_t o = off; off = (off + bytes + 255) & ~(size_t)255; return o; };
    float*    h       = (float*)((char*)d_ws + alloc((size_t)N * D * 4));
    unsigned* staging = (unsigned*)h;            // alias: 4*E*4 = 25.6MB <= N*D*4
    float*    hp      = (float*)((char*)d_ws + alloc((size_t)N * D * 4));
    float*    xnext   = (float*)((char*)d_ws + alloc((size_t)N * D * 4));
    float*    a_s     = (float*)((char*)d_ws + alloc((size_t)N * 4));
    float*    a_d     = (float*)((char*)d_ws + alloc((size_t)N * 4));
    int*      prefix  = (int*)((char*)d_ws + alloc((size_t)4 * (N + 1) * 4));
    int*      srcs    = (int*)((char*)d_ws + alloc((size_t)4 * E * 4));
    int*      bcnt    = (int*)((char*)d_ws + alloc((size_t)4 * NB * 4));
    int*      boff    = (int*)((char*)d_ws + alloc((size_t)4 * (NB + 1) * 4));
    int*      bcur    = (int*)((char*)d_ws + alloc((size_t)4 * NB * 4));
    (void)ws_size;

    const int nodeBlocks = (N + WPB - 1) / WPB;
    const int edgeBlocks = (E + 255) / 256;
    const int histBlocks = (E + 4095) / 4096;

    // ---- bucketed CSR build (edges identical for both layers) ----
    hipMemsetAsync(bcnt, 0, (size_t)4 * NB * 4, stream);
    k_bcount<<<dim3(histBlocks, 4), 256, 0, stream>>>(e0, e1, e2, e3, bcnt, E, NB);
    k_bscan<<<dim3(1, 4), 1024, 0, stream>>>(bcnt, boff, bcur, prefix, E, N, NB);
    k_bscat<<<dim3(edgeBlocks, 4), 256, 0, stream>>>(e0, e1, e2, e3, bcur, staging, E, NB);
    k_place<<<dim3(NB, 4), 256, 0, stream>>>(staging, boff, prefix, srcs, N, E, NB);

    // ---- layers ----
    for (int l = 0; l < 2; l++) {
        const float* xin = (l == 0) ? x : xnext;
        float* xout = (l == 1) ? out : xnext;
        const float* W1l = W1 + (size_t)l * 5 * D * D;

        k_mlp1x<<<nodeBlocks, BLK, 0, stream>>>(xin, W1l, b1 + l * D, hp, N);

        for (int r = 0; r < 4; r++) {
            int lr = l * 4 + r;
            k_gemm_h<<<nodeBlocks, BLK, 0, stream>>>(
                xin, gatW + (size_t)lr * D * D, atS + (size_t)lr * D, atD + (size_t)lr * D,
                h, a_s, a_d, N);
            k_agg<<<nodeBlocks, BLK, 0, stream>>>(
                h, a_s, a_d, prefix + (size_t)r * (N + 1), srcs + (size_t)r * E,
                gatB + (size_t)lr * D, W1l + (size_t)(D + r * D) * D, hp, N);
        }

        k_mlp2<<<nodeBlocks, BLK, 0, stream>>>(hp, W2 + (size_t)l * D * D, b2 + l * D, xout, N);
    }
}

// Round 3
// 2590.603 us; speedup vs baseline: 1.3173x; 1.3173x over previous
//
#include <hip/hip_runtime.h>
#include <hip/hip_bf16.h>
#include <math.h>

#define D 64
#define NEG 0.2f
#define WPB 4              // waves per block
#define BLK (WPB * 64)
#define DPB 128            // dst nodes per bucket
#define MAXNB 1024         // max buckets (N <= 131072)
#define CHUNK 16384        // edges per partition block

__device__ __forceinline__ float lrelu(float v) { return v > 0.f ? v : NEG * v; }

__device__ __forceinline__ const int* edge_ptr(const int* e0, const int* e1,
                                               const int* e2, const int* e3, int r)
{
    return (r == 0) ? e0 : (r == 1) ? e1 : (r == 2) ? e2 : e3;
}

// ---------------- bucketed CSR build ----------------

// bucket histogram (LDS-staged), reads dst row only
__global__ __launch_bounds__(256) void k_bcount(
    const int* __restrict__ e0, const int* __restrict__ e1,
    const int* __restrict__ e2, const int* __restrict__ e3,
    int* __restrict__ bcnt, int E, int NB)
{
    int r = blockIdx.y;
    const int* dst = edge_ptr(e0, e1, e2, e3, r) + E;
    __shared__ int hist[MAXNB];
    for (int i = threadIdx.x; i < NB; i += 256) hist[i] = 0;
    __syncthreads();
    int base = blockIdx.x * CHUNK;
    int end = base + CHUNK < E ? base + CHUNK : E;
    for (int i = base + threadIdx.x; i < end; i += 256)
        atomicAdd(&hist[dst[i] >> 7], 1);
    __syncthreads();
    for (int i = threadIdx.x; i < NB; i += 256)
        if (hist[i]) atomicAdd(&bcnt[r * NB + i], hist[i]);
}

// exclusive scan of bucket counts -> boff (NB+1), init bucket cursors, prefix[N]=E
__global__ __launch_bounds__(1024) void k_bscan(
    const int* __restrict__ bcnt, int* __restrict__ boff,
    int* __restrict__ bcur, int* __restrict__ prefix, int E, int N, int NB)
{
    int r = blockIdx.y;
    __shared__ int sh[1024];
    int t = threadIdx.x;
    int v = (t < NB) ? bcnt[r * NB + t] : 0;
    sh[t] = v;
    __syncthreads();
    for (int off = 1; off < 1024; off <<= 1) {
        int add = (t >= off) ? sh[t - off] : 0;
        __syncthreads();
        sh[t] += add;
        __syncthreads();
    }
    if (t < NB) {
        int excl = sh[t] - v;
        boff[r * (NB + 1) + t] = excl;
        bcur[r * NB + t] = excl;
    }
    if (t == 0) {
        boff[r * (NB + 1) + NB] = E;
        prefix[(size_t)r * (N + 1) + N] = E;
    }
}

// block-batched partition: LDS hist -> ONE global atomic per nonzero bucket
// (reserve a contiguous run) -> place at base + local rank. Low contention,
// block-contiguous writes.
__global__ __launch_bounds__(256) void k_part(
    const int* __restrict__ e0, const int* __restrict__ e1,
    const int* __restrict__ e2, const int* __restrict__ e3,
    int* __restrict__ gcur, unsigned* __restrict__ staging, int E, int NB)
{
    int r = blockIdx.y;
    const int* ep = edge_ptr(e0, e1, e2, e3, r);
    const int* srcp = ep;
    const int* dstp = ep + E;
    __shared__ int hist[MAXNB];
    __shared__ int base[MAXNB];
    for (int j = threadIdx.x; j < NB; j += 256) hist[j] = 0;
    __syncthreads();
    int begin = blockIdx.x * CHUNK;
    int end = begin + CHUNK < E ? begin + CHUNK : E;
    for (int i = begin + threadIdx.x; i < end; i += 256)
        atomicAdd(&hist[dstp[i] >> 7], 1);
    __syncthreads();
    for (int j = threadIdx.x; j < NB; j += 256) {
        int c = hist[j];
        base[j] = c ? atomicAdd(&gcur[r * NB + j], c) : 0;
        hist[j] = 0;
    }
    __syncthreads();
    unsigned* stg = staging + (size_t)r * E;
    for (int i = begin + threadIdx.x; i < end; i += 256) {
        int d = dstp[i];
        int b = d >> 7;
        int pos = base[b] + atomicAdd(&hist[b], 1);
        stg[pos] = ((unsigned)srcp[i] << 7) | (unsigned)(d & 127);
    }
}

// one block per (bucket, relation): local per-dst count+scan, write prefix, place srcs
__global__ __launch_bounds__(256) void k_place(
    const unsigned* __restrict__ staging, const int* __restrict__ boff,
    int* __restrict__ prefix, int* __restrict__ srcs, int N, int E, int NB)
{
    int r = blockIdx.y;
    int b = blockIdx.x;
    int t = threadIdx.x;
    __shared__ int lcount[DPB];
    __shared__ int ls[DPB];
    __shared__ int lcur[DPB];
    int gbase = boff[r * (NB + 1) + b];
    int bcnt = boff[r * (NB + 1) + b + 1] - gbase;
    if (t < DPB) lcount[t] = 0;
    __syncthreads();
    const unsigned* st = staging + (size_t)r * E + gbase;
    for (int i = t; i < bcnt; i += 256)
        atomicAdd(&lcount[st[i] & 127], 1);
    __syncthreads();
    if (t < DPB) ls[t] = lcount[t];
    __syncthreads();
    for (int off = 1; off < DPB; off <<= 1) {
        int add = (t < DPB && t >= off) ? ls[t - off] : 0;
        __syncthreads();
        if (t < DPB) ls[t] += add;
        __syncthreads();
    }
    int lo = b * DPB;
    if (t < DPB) {
        int excl = ls[t] - lcount[t];
        lcur[t] = excl;
        int d = lo + t;
        if (d < N) prefix[(size_t)r * (N + 1) + d] = gbase + excl;
    }
    __syncthreads();
    for (int i = t; i < bcnt; i += 256) {
        unsigned v = st[i];
        int pos = atomicAdd(&lcur[v & 127], 1);
        srcs[(size_t)r * E + gbase + pos] = (int)(v >> 7);
    }
}

// ---------------- per-layer compute ----------------

// h_r = x @ W_r (bf16 out) ; a_src_r = h.att_s_r ; a_dst_r = h.att_d_r
// one wave per (node, relation); grid.y = relation
__global__ __launch_bounds__(BLK) void k_gemm_h(
    const float* __restrict__ x, const float* __restrict__ gatW,
    const float* __restrict__ atS, const float* __restrict__ atD,
    __hip_bfloat16* __restrict__ h, float* __restrict__ a_s,
    float* __restrict__ a_d, int N)
{
    int r = blockIdx.y;
    int lane = threadIdx.x & 63;
    int n = blockIdx.x * WPB + (threadIdx.x >> 6);
    if (n >= N) return;
    const float* W = gatW + (size_t)r * D * D;
    float xv = x[(size_t)n * D + lane];
    float acc = 0.f;
#pragma unroll
    for (int k = 0; k < D; k++) acc = fmaf(__shfl(xv, k), W[k * D + lane], acc);
    h[((size_t)r * N + n) * D + lane] = __float2bfloat16(acc);
    float ps = acc * atS[r * D + lane];
    float pd = acc * atD[r * D + lane];
#pragma unroll
    for (int off = 32; off; off >>= 1) {
        ps += __shfl_xor(ps, off);
        pd += __shfl_xor(pd, off);
    }
    if (lane == 0) { a_s[(size_t)r * N + n] = ps; a_d[(size_t)r * N + n] = pd; }
}

// GAT aggregation: single-pass online softmax over CSR, writes g plane per relation.
// One wave per dst node; lane = feature dim; grid.y = relation.
__global__ __launch_bounds__(BLK) void k_agg(
    const __hip_bfloat16* __restrict__ h, const float* __restrict__ a_sall,
    const float* __restrict__ a_dall, const int* __restrict__ prefix,
    const int* __restrict__ srcsall, const float* __restrict__ gatB,
    float* __restrict__ g, int N, int E)
{
    int r = blockIdx.y;
    int lane = threadIdx.x & 63;
    int d = blockIdx.x * WPB + (threadIdx.x >> 6);
    if (d >= N) return;

    const __hip_bfloat16* hr = h + (size_t)r * N * D;
    const float* a_src = a_sall + (size_t)r * N;
    const int* starts = prefix + (size_t)r * (N + 1);
    const int* srcs = srcsall + (size_t)r * E;

    int base = starts[d];
    int cnt = starts[d + 1] - base;
    float ad = a_dall[(size_t)r * N + d];

    // self-loop initializes the online-softmax state
    float m = lrelu(a_src[d] + ad);
    float z = 1.f;                                  // exp(self - m) = 1
    float acc = __bfloat162float(hr[(size_t)d * D + lane]);

    for (int j0 = 0; j0 < cnt; j0 += 64) {
        int jj = j0 + lane;
        bool valid = jj < cnt;
        int s = valid ? srcs[base + jj] : 0;
        float a = valid ? lrelu(a_src[s] + ad) : -1e30f;
        float cm = a;
#pragma unroll
        for (int off = 32; off; off >>= 1) cm = fmaxf(cm, __shfl_xor(cm, off));
        if (cm > m) {
            float sc = __expf(m - cm);
            z *= sc;
            acc *= sc;
            m = cm;
        }
        float e = __expf(a - m);                    // 0 for invalid lanes
        int lim = (cnt - j0) < 64 ? (cnt - j0) : 64;
        for (int t = 0; t < lim; t++) {
            float et = __shfl(e, t);
            int st = __shfl(s, t);
            z += et;
            acc = fmaf(et, __bfloat162float(hr[(size_t)st * D + lane]), acc);
        }
    }

    g[((size_t)r * N + d) * D + lane] = acc / z + gatB[r * D + lane];
}

// fused MLP: out = tanh(b1 + x@W1x + sum_r g_r@W1r) @ W2 + b2 ; 2 nodes per wave
__global__ __launch_bounds__(BLK) void k_mlp(
    const float* __restrict__ x, const float* __restrict__ g,
    const float* __restrict__ W1, const float* __restrict__ b1,
    const float* __restrict__ W2, const float* __restrict__ b2,
    float* __restrict__ xout, int N)
{
    int lane = threadIdx.x & 63;
    int n0 = (blockIdx.x * WPB + (threadIdx.x >> 6)) * 2;
    if (n0 >= N) return;
    bool two = (n0 + 1) < N;
    int n1 = two ? n0 + 1 : n0;

    float acc0 = b1[lane], acc1 = acc0;
    {
        float v0 = x[(size_t)n0 * D + lane];
        float v1 = x[(size_t)n1 * D + lane];
#pragma unroll
        for (int k = 0; k < D; k++) {
            float w = W1[k * D + lane];
            acc0 = fmaf(__shfl(v0, k), w, acc0);
            acc1 = fmaf(__shfl(v1, k), w, acc1);
        }
    }
    for (int r = 0; r < 4; r++) {
        const float* Wr = W1 + (size_t)(D + r * D) * D;
        float v0 = g[((size_t)r * N + n0) * D + lane];
        float v1 = g[((size_t)r * N + n1) * D + lane];
#pragma unroll
        for (int k = 0; k < D; k++) {
            float w = Wr[k * D + lane];
            acc0 = fmaf(__shfl(v0, k), w, acc0);
            acc1 = fmaf(__shfl(v1, k), w, acc1);
        }
    }
    float h0 = tanhf(acc0);
    float h1 = tanhf(acc1);
    float o0 = b2[lane], o1 = o0;
#pragma unroll
    for (int k = 0; k < D; k++) {
        float w = W2[k * D + lane];
        o0 = fmaf(__shfl(h0, k), w, o0);
        o1 = fmaf(__shfl(h1, k), w, o1);
    }
    xout[(size_t)n0 * D + lane] = o0;
    if (two) xout[(size_t)n1 * D + lane] = o1;
}

// ---------------- launch ----------------

extern "C" void kernel_launch(void* const* d_in, const int* in_sizes, int n_in,
                              void* d_out, int out_size, void* d_ws, size_t ws_size,
                              hipStream_t stream)
{
    const float* x    = (const float*)d_in[0];
    const int*   e0   = (const int*)d_in[1];
    const int*   e1   = (const int*)d_in[2];
    const int*   e2   = (const int*)d_in[3];
    const int*   e3   = (const int*)d_in[4];
    const float* gatW = (const float*)d_in[5];   // (2,4,64,64)
    const float* atS  = (const float*)d_in[6];   // (2,4,64)
    const float* atD  = (const float*)d_in[7];
    const float* gatB = (const float*)d_in[8];
    const float* W1   = (const float*)d_in[9];   // (2,320,64)
    const float* b1   = (const float*)d_in[10];  // (2,64)
    const float* W2   = (const float*)d_in[11];  // (2,64,64)
    const float* b2   = (const float*)d_in[12];  // (2,64)
    float* out = (float*)d_out;

    const int N = in_sizes[0] / D;
    const int E = in_sizes[1] / 2;
    const int NB = (N + DPB - 1) / DPB;          // buckets per relation

    size_t off = 0;
    auto alloc = [&](size_t bytes) { size_t o = off; off = (off + bytes + 255) & ~(size_t)255; return o; };
    __hip_bfloat16* h  = (__hip_bfloat16*)((char*)d_ws + alloc((size_t)4 * N * D * 2));
    float*    g       = (float*)((char*)d_ws + alloc((size_t)4 * N * D * 4));
    unsigned* staging = (unsigned*)g;            // alias: CSR build precedes g use
    float*    xnext   = (float*)((char*)d_ws + alloc((size_t)N * D * 4));
    float*    a_s     = (float*)((char*)d_ws + alloc((size_t)4 * N * 4));
    float*    a_d     = (float*)((char*)d_ws + alloc((size_t)4 * N * 4));
    int*      prefix  = (int*)((char*)d_ws + alloc((size_t)4 * (N + 1) * 4));
    int*      srcs    = (int*)((char*)d_ws + alloc((size_t)4 * E * 4));
    int*      bcnt    = (int*)((char*)d_ws + alloc((size_t)4 * NB * 4));
    int*      boff    = (int*)((char*)d_ws + alloc((size_t)4 * (NB + 1) * 4));
    int*      bcur    = (int*)((char*)d_ws + alloc((size_t)4 * NB * 4));
    (void)ws_size;

    const int nodeBlocks = (N + WPB - 1) / WPB;
    const int partBlocks = (E + CHUNK - 1) / CHUNK;
    const int mlpBlocks = ((N + 1) / 2 + WPB - 1) / WPB;

    // ---- bucketed CSR build (edges identical for both layers) ----
    hipMemsetAsync(bcnt, 0, (size_t)4 * NB * 4, stream);
    k_bcount<<<dim3(partBlocks, 4), 256, 0, stream>>>(e0, e1, e2, e3, bcnt, E, NB);
    k_bscan<<<dim3(1, 4), 1024, 0, stream>>>(bcnt, boff, bcur, prefix, E, N, NB);
    k_part<<<dim3(partBlocks, 4), 256, 0, stream>>>(e0, e1, e2, e3, bcur, staging, E, NB);
    k_place<<<dim3(NB, 4), 256, 0, stream>>>(staging, boff, prefix, srcs, N, E, NB);

    // ---- layers ----
    for (int l = 0; l < 2; l++) {
        const float* xin = (l == 0) ? x : xnext;
        float* xout = (l == 1) ? out : xnext;
        int lr0 = l * 4;

        k_gemm_h<<<dim3(nodeBlocks, 4), BLK, 0, stream>>>(
            xin, gatW + (size_t)lr0 * D * D, atS + (size_t)lr0 * D, atD + (size_t)lr0 * D,
            h, a_s, a_d, N);
        k_agg<<<dim3(nodeBlocks, 4), BLK, 0, stream>>>(
            h, a_s, a_d, prefix, srcs, gatB + (size_t)lr0 * D, g, N, E);
        k_mlp<<<mlpBlocks, BLK, 0, stream>>>(
            xin, g, W1 + (size_t)l * 5 * D * D, b1 + l * D,
            W2 + (size_t)l * D * D, b2 + l * D, xout, N);
    }
}

// Round 4
// 960.430 us; speedup vs baseline: 3.5531x; 2.6973x over previous
//
#include <hip/hip_runtime.h>
#include <hip/hip_bf16.h>
#include <math.h>

#define D 64
#define NEG 0.2f
#define WPB 4
#define BLK 256
#define DPB 128
#define MAXNB 1024
#define CHUNK 16384

typedef __attribute__((ext_vector_type(8))) short bf8;
typedef __attribute__((ext_vector_type(4))) float f4;
typedef __attribute__((ext_vector_type(4))) int i4;

__device__ __forceinline__ float lrelu(float v) { return v > 0.f ? v : NEG * v; }

__device__ __forceinline__ unsigned short f2bf(float f) {
    unsigned u = __float_as_uint(f);
    u = (u + 0x7fffu + ((u >> 16) & 1u)) >> 16;   // RTNE
    return (unsigned short)u;
}
__device__ __forceinline__ float bf2f(unsigned short u) {
    return __uint_as_float(((unsigned)u) << 16);
}
__device__ __forceinline__ bf8 ld_frag_g(const unsigned short* p) {
    i4 v = *(const i4*)p;
    return __builtin_bit_cast(bf8, v);
}

__device__ __forceinline__ const int* edge_ptr(const int* e0, const int* e1,
                                               const int* e2, const int* e3, int r)
{
    return (r == 0) ? e0 : (r == 1) ? e1 : (r == 2) ? e2 : e3;
}

// ---------------- bucketed CSR build (unchanged from R3) ----------------

__global__ __launch_bounds__(256) void k_bcount(
    const int* __restrict__ e0, const int* __restrict__ e1,
    const int* __restrict__ e2, const int* __restrict__ e3,
    int* __restrict__ bcnt, int E, int NB)
{
    int r = blockIdx.y;
    const int* dst = edge_ptr(e0, e1, e2, e3, r) + E;
    __shared__ int hist[MAXNB];
    for (int i = threadIdx.x; i < NB; i += 256) hist[i] = 0;
    __syncthreads();
    int base = blockIdx.x * CHUNK;
    int end = base + CHUNK < E ? base + CHUNK : E;
    for (int i = base + threadIdx.x; i < end; i += 256)
        atomicAdd(&hist[dst[i] >> 7], 1);
    __syncthreads();
    for (int i = threadIdx.x; i < NB; i += 256)
        if (hist[i]) atomicAdd(&bcnt[r * NB + i], hist[i]);
}

__global__ __launch_bounds__(1024) void k_bscan(
    const int* __restrict__ bcnt, int* __restrict__ boff,
    int* __restrict__ bcur, int* __restrict__ prefix, int E, int N, int NB)
{
    int r = blockIdx.y;
    __shared__ int sh[1024];
    int t = threadIdx.x;
    int v = (t < NB) ? bcnt[r * NB + t] : 0;
    sh[t] = v;
    __syncthreads();
    for (int off = 1; off < 1024; off <<= 1) {
        int add = (t >= off) ? sh[t - off] : 0;
        __syncthreads();
        sh[t] += add;
        __syncthreads();
    }
    if (t < NB) {
        int excl = sh[t] - v;
        boff[r * (NB + 1) + t] = excl;
        bcur[r * NB + t] = excl;
    }
    if (t == 0) {
        boff[r * (NB + 1) + NB] = E;
        prefix[(size_t)r * (N + 1) + N] = E;
    }
}

__global__ __launch_bounds__(256) void k_part(
    const int* __restrict__ e0, const int* __restrict__ e1,
    const int* __restrict__ e2, const int* __restrict__ e3,
    int* __restrict__ gcur, unsigned* __restrict__ staging, int E, int NB)
{
    int r = blockIdx.y;
    const int* ep = edge_ptr(e0, e1, e2, e3, r);
    const int* srcp = ep;
    const int* dstp = ep + E;
    __shared__ int hist[MAXNB];
    __shared__ int base[MAXNB];
    for (int j = threadIdx.x; j < NB; j += 256) hist[j] = 0;
    __syncthreads();
    int begin = blockIdx.x * CHUNK;
    int end = begin + CHUNK < E ? begin + CHUNK : E;
    for (int i = begin + threadIdx.x; i < end; i += 256)
        atomicAdd(&hist[dstp[i] >> 7], 1);
    __syncthreads();
    for (int j = threadIdx.x; j < NB; j += 256) {
        int c = hist[j];
        base[j] = c ? atomicAdd(&gcur[r * NB + j], c) : 0;
        hist[j] = 0;
    }
    __syncthreads();
    unsigned* stg = staging + (size_t)r * E;
    for (int i = begin + threadIdx.x; i < end; i += 256) {
        int d = dstp[i];
        int b = d >> 7;
        int pos = base[b] + atomicAdd(&hist[b], 1);
        stg[pos] = ((unsigned)srcp[i] << 7) | (unsigned)(d & 127);
    }
}

__global__ __launch_bounds__(256) void k_place(
    const unsigned* __restrict__ staging, const int* __restrict__ boff,
    int* __restrict__ prefix, int* __restrict__ srcs, int N, int E, int NB)
{
    int r = blockIdx.y;
    int b = blockIdx.x;
    int t = threadIdx.x;
    __shared__ int lcount[DPB];
    __shared__ int ls[DPB];
    __shared__ int lcur[DPB];
    int gbase = boff[r * (NB + 1) + b];
    int bcnt = boff[r * (NB + 1) + b + 1] - gbase;
    if (t < DPB) lcount[t] = 0;
    __syncthreads();
    const unsigned* st = staging + (size_t)r * E + gbase;
    for (int i = t; i < bcnt; i += 256)
        atomicAdd(&lcount[st[i] & 127], 1);
    __syncthreads();
    if (t < DPB) ls[t] = lcount[t];
    __syncthreads();
    for (int off = 1; off < DPB; off <<= 1) {
        int add = (t < DPB && t >= off) ? ls[t - off] : 0;
        __syncthreads();
        if (t < DPB) ls[t] += add;
        __syncthreads();
    }
    int lo = b * DPB;
    if (t < DPB) {
        int excl = ls[t] - lcount[t];
        lcur[t] = excl;
        int d = lo + t;
        if (d < N) prefix[(size_t)r * (N + 1) + d] = gbase + excl;
    }
    __syncthreads();
    for (int i = t; i < bcnt; i += 256) {
        unsigned v = st[i];
        int pos = atomicAdd(&lcur[v & 127], 1);
        srcs[(size_t)r * E + gbase + pos] = (int)(v >> 7);
    }
}

// ---------------- setup: cast + weight packing ----------------

__global__ __launch_bounds__(256) void k_xcast(
    const float* __restrict__ x, unsigned short* __restrict__ xb, int n4)
{
    int i = blockIdx.x * 256 + threadIdx.x;
    if (i < n4) {
        float4 v = ((const float4*)x)[i];
        ushort4 o;
        o.x = f2bf(v.x); o.y = f2bf(v.y); o.z = f2bf(v.z); o.w = f2bf(v.w);
        ((ushort4*)xb)[i] = o;
    }
}

// Pack weights into B-fragment layout for mfma_f32_16x16x32_bf16:
// lane L holds B[k = kc*32 + (L>>4)*8 + j][c = ct*16 + (L&15)], j=0..7.
// Frags: f<80: gat (m=l*4+r, slot kc*5+ct; ct==4 => cols {W att_s, W att_d})
//        80<=f<160: W1 (l*40 + kc*4+ct, K=320)
//        160<=f<176: W2 (l*8 + kc*4+ct)
__global__ __launch_bounds__(64) void k_pack(
    const float* __restrict__ gatW, const float* __restrict__ atS,
    const float* __restrict__ atD, const float* __restrict__ W1,
    const float* __restrict__ W2, unsigned short* __restrict__ WgP,
    unsigned short* __restrict__ W1P, unsigned short* __restrict__ W2P)
{
    int f = blockIdx.x;
    int L = threadIdx.x;
    int kg = L >> 4, c = L & 15;
    unsigned short vals[8];
    unsigned short* dst;
    if (f < 80) {
        int m = f / 10, rem = f % 10;
        int l = m / 4, r = m % 4;
        int kc = rem / 5, ct = rem % 5;
        const float* W = gatW + (size_t)(l * 4 + r) * D * D;
        if (ct < 4) {
#pragma unroll
            for (int j = 0; j < 8; j++) {
                int k = kc * 32 + kg * 8 + j;
                vals[j] = f2bf(W[k * D + ct * 16 + c]);
            }
        } else {
            const float* att = (c == 0) ? atS + (size_t)(l * 4 + r) * D
                                        : atD + (size_t)(l * 4 + r) * D;
#pragma unroll
            for (int j = 0; j < 8; j++) {
                int k = kc * 32 + kg * 8 + j;
                float s = 0.f;
                if (c < 2)
                    for (int cc = 0; cc < D; cc++) s += W[k * D + cc] * att[cc];
                vals[j] = f2bf(s);
            }
        }
        dst = WgP + ((size_t)f * 64 + L) * 8;
    } else if (f < 160) {
        int f2 = f - 80;
        int l = f2 / 40, rem = f2 % 40;
        int kc = rem / 4, ct = rem % 4;
        const float* W = W1 + (size_t)l * 5 * D * D;   // [320][64]
#pragma unroll
        for (int j = 0; j < 8; j++) {
            int k = kc * 32 + kg * 8 + j;
            vals[j] = f2bf(W[k * D + ct * 16 + c]);
        }
        dst = W1P + ((size_t)f2 * 64 + L) * 8;
    } else {
        int f3 = f - 160;
        int l = f3 / 8, rem = f3 % 8;
        int kc = rem / 4, ct = rem % 4;
        const float* W = W2 + (size_t)l * D * D;
#pragma unroll
        for (int j = 0; j < 8; j++) {
            int k = kc * 32 + kg * 8 + j;
            vals[j] = f2bf(W[k * D + ct * 16 + c]);
        }
        dst = W2P + ((size_t)f3 * 64 + L) * 8;
    }
    i4 v;
    short8_store:;
    v = __builtin_bit_cast(i4, *(bf8*)vals);
    *(i4*)dst = v;
}

// ---------------- MFMA compute ----------------

// h_r = xb @ W_r (bf16 out); cols 64..65 of the widened B give a_src, a_dst.
// Block = 4 waves x 16 nodes; grid (ceil(N/64), 4 relations).
__global__ __launch_bounds__(BLK) void k_gemm_h(
    const unsigned short* __restrict__ xb, const unsigned short* __restrict__ WgPl,
    unsigned short* __restrict__ h, float* __restrict__ a_s,
    float* __restrict__ a_d, int N)
{
    int r = blockIdx.y;
    int w = threadIdx.x >> 6, L = threadIdx.x & 63;
    int n0 = blockIdx.x * 64 + w * 16;
    int lo = L & 15, kg = L >> 4;
    int nA = n0 + lo; if (nA >= N) nA = N - 1;
    bf8 a0 = ld_frag_g(xb + (size_t)nA * D + kg * 8);
    bf8 a1 = ld_frag_g(xb + (size_t)nA * D + 32 + kg * 8);
    const unsigned short* Wbase = WgPl + (size_t)r * 10 * 512;
#pragma unroll
    for (int ct = 0; ct < 5; ct++) {
        f4 acc = {0.f, 0.f, 0.f, 0.f};
        bf8 b0 = ld_frag_g(Wbase + (size_t)ct * 512 + L * 8);
        bf8 b1 = ld_frag_g(Wbase + (size_t)(5 + ct) * 512 + L * 8);
        acc = __builtin_amdgcn_mfma_f32_16x16x32_bf16(a0, b0, acc, 0, 0, 0);
        acc = __builtin_amdgcn_mfma_f32_16x16x32_bf16(a1, b1, acc, 0, 0, 0);
#pragma unroll
        for (int q = 0; q < 4; q++) {
            int node = n0 + kg * 4 + q;
            if (node < N) {
                if (ct < 4)
                    h[((size_t)r * N + node) * D + ct * 16 + lo] = f2bf(acc[q]);
                else if (lo == 0)
                    a_s[(size_t)r * N + node] = acc[q];
                else if (lo == 1)
                    a_d[(size_t)r * N + node] = acc[q];
            }
        }
    }
}

// GAT aggregation: softmax without max-subtraction (alphas are O(10)).
// One wave per dst; lane = feature. Pair buffer in LDS for (s, e) broadcast.
__global__ __launch_bounds__(BLK) void k_agg(
    const unsigned short* __restrict__ h, const float* __restrict__ a_sall,
    const float* __restrict__ a_dall, const int* __restrict__ prefix,
    const int* __restrict__ srcsall, const float* __restrict__ gatB,
    unsigned short* __restrict__ g, int N, int E)
{
    __shared__ int2 pairs[WPB][64];
    int r = blockIdx.y;
    int w = threadIdx.x >> 6, lane = threadIdx.x & 63;
    int d = blockIdx.x * WPB + w;
    if (d >= N) d = N - 1;                    // clamped duplicate work, same store value

    const unsigned short* hr = h + (size_t)r * N * D;
    const float* a_src = a_sall + (size_t)r * N;
    const int* starts = prefix + (size_t)r * (N + 1);
    const int* srcs = srcsall + (size_t)r * E;

    int base = starts[d];
    int cnt = starts[d + 1] - base;
    float ad = a_dall[(size_t)r * N + d];

    float ez = __expf(lrelu(a_src[d] + ad));  // self-loop
    float z = ez;
    float acc = ez * bf2f(hr[(size_t)d * D + lane]);

    for (int j0 = 0; j0 < cnt; j0 += 64) {
        int jj = j0 + lane;
        bool valid = jj < cnt;
        int s = valid ? srcs[base + jj] : 0;
        float e = valid ? __expf(lrelu(a_src[s] + ad)) : 0.f;
        pairs[w][lane] = make_int2(s, __float_as_int(e));
        __threadfence_block();                // in-wave LDS write->read ordering
        int lim = cnt - j0; if (lim > 64) lim = 64;
        for (int t = 0; t < lim; t += 2) {
            int4 pv = *(int4*)(&pairs[w][t]);
            float e0 = __int_as_float(pv.y);
            float e1 = __int_as_float(pv.w);  // 0 beyond lim -> contributes nothing
            z += e0 + e1;
            acc = fmaf(e0, bf2f(hr[(size_t)pv.x * D + lane]), acc);
            acc = fmaf(e1, bf2f(hr[(size_t)pv.z * D + lane]), acc);
        }
        __threadfence_block();                // reads done before next chunk's writes
    }

    g[((size_t)r * N + d) * D + lane] = f2bf(acc / z + gatB[r * D + lane]);
}

// fused MLP: out = tanh(b1 + [xb|g0..g3] @ W1) @ W2 + b2
// Block = 4 waves x 16 nodes. Hidden transposed D-layout -> A-layout via LDS.
__global__ __launch_bounds__(BLK) void k_mlp(
    const unsigned short* __restrict__ xb, const unsigned short* __restrict__ g,
    const unsigned short* __restrict__ W1Pl, const float* __restrict__ b1l,
    const unsigned short* __restrict__ W2Pl, const float* __restrict__ b2l,
    void* __restrict__ outp, int N, int last)
{
    __shared__ unsigned short sh[WPB][16 * 80];   // row stride 80 bf16 (160 B)
    int w = threadIdx.x >> 6, L = threadIdx.x & 63;
    int n0 = blockIdx.x * 64 + w * 16;
    int lo = L & 15, kg = L >> 4;
    int nA = n0 + lo; if (nA >= N) nA = N - 1;

    f4 acc[4];
#pragma unroll
    for (int ct = 0; ct < 4; ct++) acc[ct] = (f4){0.f, 0.f, 0.f, 0.f};

#pragma unroll
    for (int p = 0; p < 5; p++) {
        const unsigned short* plane = (p == 0) ? xb : g + (size_t)(p - 1) * N * D;
#pragma unroll
        for (int kc2 = 0; kc2 < 2; kc2++) {
            bf8 a = ld_frag_g(plane + (size_t)nA * D + kc2 * 32 + kg * 8);
            int kc = p * 2 + kc2;
#pragma unroll
            for (int ct = 0; ct < 4; ct++) {
                bf8 b = ld_frag_g(W1Pl + ((size_t)(kc * 4 + ct) * 512 + L * 8));
                acc[ct] = __builtin_amdgcn_mfma_f32_16x16x32_bf16(a, b, acc[ct], 0, 0, 0);
            }
        }
    }

    // bias + tanh, write to LDS in row-major [node16][col64]
    unsigned short* tile = &sh[w][0];
#pragma unroll
    for (int ct = 0; ct < 4; ct++) {
        float bb = b1l[ct * 16 + lo];
#pragma unroll
        for (int q = 0; q < 4; q++)
            tile[(kg * 4 + q) * 80 + ct * 16 + lo] = f2bf(tanhf(acc[ct][q] + bb));
    }
    __syncthreads();

    f4 o[4];
#pragma unroll
    for (int ct = 0; ct < 4; ct++) o[ct] = (f4){0.f, 0.f, 0.f, 0.f};
#pragma unroll
    for (int kc = 0; kc < 2; kc++) {
        const unsigned short* ap = tile + lo * 80 + kc * 32 + kg * 8;
        i4 av = *(const i4*)ap;
        bf8 a = __builtin_bit_cast(bf8, av);
#pragma unroll
        for (int ct = 0; ct < 4; ct++) {
            bf8 b = ld_frag_g(W2Pl + ((size_t)(kc * 4 + ct) * 512 + L * 8));
            o[ct] = __builtin_amdgcn_mfma_f32_16x16x32_bf16(a, b, o[ct], 0, 0, 0);
        }
    }
#pragma unroll
    for (int ct = 0; ct < 4; ct++) {
        float bb = b2l[ct * 16 + lo];
#pragma unroll
        for (int q = 0; q < 4; q++) {
            int node = n0 + kg * 4 + q;
            if (node < N) {
                int col = ct * 16 + lo;
                float v = o[ct][q] + bb;
                if (last) ((float*)outp)[(size_t)node * D + col] = v;
                else ((unsigned short*)outp)[(size_t)node * D + col] = f2bf(v);
            }
        }
    }
}

// ---------------- launch ----------------

extern "C" void kernel_launch(void* const* d_in, const int* in_sizes, int n_in,
                              void* d_out, int out_size, void* d_ws, size_t ws_size,
                              hipStream_t stream)
{
    const float* x    = (const float*)d_in[0];
    const int*   e0   = (const int*)d_in[1];
    const int*   e1   = (const int*)d_in[2];
    const int*   e2   = (const int*)d_in[3];
    const int*   e3   = (const int*)d_in[4];
    const float* gatW = (const float*)d_in[5];
    const float* atS  = (const float*)d_in[6];
    const float* atD  = (const float*)d_in[7];
    const float* gatB = (const float*)d_in[8];
    const float* W1   = (const float*)d_in[9];
    const float* b1   = (const float*)d_in[10];
    const float* W2   = (const float*)d_in[11];
    const float* b2   = (const float*)d_in[12];
    float* out = (float*)d_out;

    const int N = in_sizes[0] / D;
    const int E = in_sizes[1] / 2;
    const int NB = (N + DPB - 1) / DPB;

    size_t off = 0;
    auto alloc = [&](size_t bytes) { size_t o = off; off = (off + bytes + 255) & ~(size_t)255; return o; };
    unsigned short* xb    = (unsigned short*)((char*)d_ws + alloc((size_t)N * D * 2));
    unsigned short* xnext = (unsigned short*)((char*)d_ws + alloc((size_t)N * D * 2));
    unsigned short* h     = (unsigned short*)((char*)d_ws + alloc((size_t)4 * N * D * 2));
    unsigned short* g     = (unsigned short*)((char*)d_ws + alloc((size_t)4 * N * D * 2));
    unsigned* staging = (unsigned*)g;        // alias: CSR build precedes g use (4E*4 <= 4ND*2)
    float* a_s   = (float*)((char*)d_ws + alloc((size_t)4 * N * 4));
    float* a_d   = (float*)((char*)d_ws + alloc((size_t)4 * N * 4));
    int* prefix  = (int*)((char*)d_ws + alloc((size_t)4 * (N + 1) * 4));
    int* srcs    = (int*)((char*)d_ws + alloc((size_t)4 * E * 4));
    int* bcnt    = (int*)((char*)d_ws + alloc((size_t)4 * NB * 4));
    int* boff    = (int*)((char*)d_ws + alloc((size_t)4 * (NB + 1) * 4));
    int* bcur    = (int*)((char*)d_ws + alloc((size_t)4 * NB * 4));
    unsigned short* WgP = (unsigned short*)((char*)d_ws + alloc((size_t)80 * 512 * 2));
    unsigned short* W1P = (unsigned short*)((char*)d_ws + alloc((size_t)80 * 512 * 2));
    unsigned short* W2P = (unsigned short*)((char*)d_ws + alloc((size_t)16 * 512 * 2));
    (void)ws_size;

    const int partBlocks = (E + CHUNK - 1) / CHUNK;
    const int tileBlocks = (N + 63) / 64;
    const int aggBlocks  = (N + WPB - 1) / WPB;

    // setup
    k_pack<<<176, 64, 0, stream>>>(gatW, atS, atD, W1, W2, WgP, W1P, W2P);
    k_xcast<<<(N * D / 4 + 255) / 256, 256, 0, stream>>>(x, xb, N * D / 4);

    // CSR build
    hipMemsetAsync(bcnt, 0, (size_t)4 * NB * 4, stream);
    k_bcount<<<dim3(partBlocks, 4), 256, 0, stream>>>(e0, e1, e2, e3, bcnt, E, NB);
    k_bscan<<<dim3(1, 4), 1024, 0, stream>>>(bcnt, boff, bcur, prefix, E, N, NB);
    k_part<<<dim3(partBlocks, 4), 256, 0, stream>>>(e0, e1, e2, e3, bcur, staging, E, NB);
    k_place<<<dim3(NB, 4), 256, 0, stream>>>(staging, boff, prefix, srcs, N, E, NB);

    // layers
    for (int l = 0; l < 2; l++) {
        const unsigned short* xin = (l == 0) ? xb : xnext;
        void* xout = (l == 1) ? (void*)out : (void*)xnext;

        k_gemm_h<<<dim3(tileBlocks, 4), BLK, 0, stream>>>(
            xin, WgP + (size_t)l * 4 * 10 * 512, h, a_s, a_d, N);
        k_agg<<<dim3(aggBlocks, 4), BLK, 0, stream>>>(
            h, a_s, a_d, prefix, srcs, gatB + (size_t)l * 4 * D, g, N, E);
        k_mlp<<<tileBlocks, BLK, 0, stream>>>(
            xin, g, W1P + (size_t)l * 40 * 512, b1 + (size_t)l * D,
            W2P + (size_t)l * 8 * 512, b2 + (size_t)l * D,
            xout, N, l == 1 ? 1 : 0);
    }
}

// Round 5
// 844.055 us; speedup vs baseline: 4.0430x; 1.1379x over previous
//
#include <hip/hip_runtime.h>
#include <hip/hip_bf16.h>
#include <math.h>

#define D 64
#define NEG 0.2f
#define WPB 4
#define BLK 256
#define DPB 128
#define MAXNB 1024
#define CHUNK 16384

typedef __attribute__((ext_vector_type(8))) short bf8;
typedef __attribute__((ext_vector_type(4))) float f4;
typedef __attribute__((ext_vector_type(4))) int i4;

__device__ __forceinline__ float lrelu(float v) { return v > 0.f ? v : NEG * v; }

__device__ __forceinline__ unsigned short f2bf(float f) {
    unsigned u = __float_as_uint(f);
    u = (u + 0x7fffu + ((u >> 16) & 1u)) >> 16;   // RTNE
    return (unsigned short)u;
}
__device__ __forceinline__ float bf2f(unsigned short u) {
    return __uint_as_float(((unsigned)u) << 16);
}
__device__ __forceinline__ bf8 ld_frag_g(const unsigned short* p) {
    i4 v = *(const i4*)p;
    return __builtin_bit_cast(bf8, v);
}

__device__ __forceinline__ const int* edge_ptr(const int* e0, const int* e1,
                                               const int* e2, const int* e3, int r)
{
    return (r == 0) ? e0 : (r == 1) ? e1 : (r == 2) ? e2 : e3;
}

// ---------------- bucketed CSR build ----------------

__global__ __launch_bounds__(256) void k_bcount(
    const int* __restrict__ e0, const int* __restrict__ e1,
    const int* __restrict__ e2, const int* __restrict__ e3,
    int* __restrict__ bcnt, int E, int NB)
{
    int r = blockIdx.y;
    const int* dst = edge_ptr(e0, e1, e2, e3, r) + E;
    __shared__ int hist[MAXNB];
    for (int i = threadIdx.x; i < NB; i += 256) hist[i] = 0;
    __syncthreads();
    int base = blockIdx.x * CHUNK;
    int end = base + CHUNK < E ? base + CHUNK : E;
    for (int i = base + threadIdx.x; i < end; i += 256)
        atomicAdd(&hist[dst[i] >> 7], 1);
    __syncthreads();
    for (int i = threadIdx.x; i < NB; i += 256)
        if (hist[i]) atomicAdd(&bcnt[r * NB + i], hist[i]);
}

__global__ __launch_bounds__(1024) void k_bscan(
    const int* __restrict__ bcnt, int* __restrict__ boff,
    int* __restrict__ bcur, int* __restrict__ prefix, int E, int N, int NB)
{
    int r = blockIdx.y;
    __shared__ int sh[1024];
    int t = threadIdx.x;
    int v = (t < NB) ? bcnt[r * NB + t] : 0;
    sh[t] = v;
    __syncthreads();
    for (int off = 1; off < 1024; off <<= 1) {
        int add = (t >= off) ? sh[t - off] : 0;
        __syncthreads();
        sh[t] += add;
        __syncthreads();
    }
    if (t < NB) {
        int excl = sh[t] - v;
        boff[r * (NB + 1) + t] = excl;
        bcur[r * NB + t] = excl;
    }
    if (t == 0) {
        boff[r * (NB + 1) + NB] = E;
        prefix[(size_t)r * (N + 1) + N] = E;
    }
}

__global__ __launch_bounds__(256) void k_part(
    const int* __restrict__ e0, const int* __restrict__ e1,
    const int* __restrict__ e2, const int* __restrict__ e3,
    int* __restrict__ gcur, unsigned* __restrict__ staging, int E, int NB)
{
    int r = blockIdx.y;
    const int* ep = edge_ptr(e0, e1, e2, e3, r);
    const int* srcp = ep;
    const int* dstp = ep + E;
    __shared__ int hist[MAXNB];
    __shared__ int base[MAXNB];
    for (int j = threadIdx.x; j < NB; j += 256) hist[j] = 0;
    __syncthreads();
    int begin = blockIdx.x * CHUNK;
    int end = begin + CHUNK < E ? begin + CHUNK : E;
    for (int i = begin + threadIdx.x; i < end; i += 256)
        atomicAdd(&hist[dstp[i] >> 7], 1);
    __syncthreads();
    for (int j = threadIdx.x; j < NB; j += 256) {
        int c = hist[j];
        base[j] = c ? atomicAdd(&gcur[r * NB + j], c) : 0;
        hist[j] = 0;
    }
    __syncthreads();
    unsigned* stg = staging + (size_t)r * E;
    for (int i = begin + threadIdx.x; i < end; i += 256) {
        int d = dstp[i];
        int b = d >> 7;
        int pos = base[b] + atomicAdd(&hist[b], 1);
        stg[pos] = ((unsigned)srcp[i] << 7) | (unsigned)(d & 127);
    }
}

__global__ __launch_bounds__(256) void k_place(
    const unsigned* __restrict__ staging, const int* __restrict__ boff,
    int* __restrict__ prefix, int* __restrict__ srcs, int N, int E, int NB)
{
    int r = blockIdx.y;
    int b = blockIdx.x;
    int t = threadIdx.x;
    __shared__ int lcount[DPB];
    __shared__ int ls[DPB];
    __shared__ int lcur[DPB];
    int gbase = boff[r * (NB + 1) + b];
    int bcnt = boff[r * (NB + 1) + b + 1] - gbase;
    if (t < DPB) lcount[t] = 0;
    __syncthreads();
    const unsigned* st = staging + (size_t)r * E + gbase;
    for (int i = t; i < bcnt; i += 256)
        atomicAdd(&lcount[st[i] & 127], 1);
    __syncthreads();
    if (t < DPB) ls[t] = lcount[t];
    __syncthreads();
    for (int off = 1; off < DPB; off <<= 1) {
        int add = (t < DPB && t >= off) ? ls[t - off] : 0;
        __syncthreads();
        if (t < DPB) ls[t] += add;
        __syncthreads();
    }
    int lo = b * DPB;
    if (t < DPB) {
        int excl = ls[t] - lcount[t];
        lcur[t] = excl;
        int d = lo + t;
        if (d < N) prefix[(size_t)r * (N + 1) + d] = gbase + excl;
    }
    __syncthreads();
    for (int i = t; i < bcnt; i += 256) {
        unsigned v = st[i];
        int pos = atomicAdd(&lcur[v & 127], 1);
        srcs[(size_t)r * E + gbase + pos] = (int)(v >> 7);
    }
}

// ---------------- setup: cast + weight packing ----------------

__global__ __launch_bounds__(256) void k_xcast(
    const float* __restrict__ x, unsigned short* __restrict__ xb, int n4)
{
    int i = blockIdx.x * 256 + threadIdx.x;
    if (i < n4) {
        float4 v = ((const float4*)x)[i];
        ushort4 o;
        o.x = f2bf(v.x); o.y = f2bf(v.y); o.z = f2bf(v.z); o.w = f2bf(v.w);
        ((ushort4*)xb)[i] = o;
    }
}

__global__ __launch_bounds__(64) void k_pack(
    const float* __restrict__ gatW, const float* __restrict__ atS,
    const float* __restrict__ atD, const float* __restrict__ W1,
    const float* __restrict__ W2, unsigned short* __restrict__ WgP,
    unsigned short* __restrict__ W1P, unsigned short* __restrict__ W2P)
{
    int f = blockIdx.x;
    int L = threadIdx.x;
    int kg = L >> 4, c = L & 15;
    unsigned short vals[8];
    unsigned short* dst;
    if (f < 80) {
        int m = f / 10, rem = f % 10;
        int l = m / 4, r = m % 4;
        int kc = rem / 5, ct = rem % 5;
        const float* W = gatW + (size_t)(l * 4 + r) * D * D;
        if (ct < 4) {
#pragma unroll
            for (int j = 0; j < 8; j++) {
                int k = kc * 32 + kg * 8 + j;
                vals[j] = f2bf(W[k * D + ct * 16 + c]);
            }
        } else {
            const float* att = (c == 0) ? atS + (size_t)(l * 4 + r) * D
                                        : atD + (size_t)(l * 4 + r) * D;
#pragma unroll
            for (int j = 0; j < 8; j++) {
                int k = kc * 32 + kg * 8 + j;
                float s = 0.f;
                if (c < 2)
                    for (int cc = 0; cc < D; cc++) s += W[k * D + cc] * att[cc];
                vals[j] = f2bf(s);
            }
        }
        dst = WgP + ((size_t)f * 64 + L) * 8;
    } else if (f < 160) {
        int f2 = f - 80;
        int l = f2 / 40, rem = f2 % 40;
        int kc = rem / 4, ct = rem % 4;
        const float* W = W1 + (size_t)l * 5 * D * D;
#pragma unroll
        for (int j = 0; j < 8; j++) {
            int k = kc * 32 + kg * 8 + j;
            vals[j] = f2bf(W[k * D + ct * 16 + c]);
        }
        dst = W1P + ((size_t)f2 * 64 + L) * 8;
    } else {
        int f3 = f - 160;
        int l = f3 / 8, rem = f3 % 8;
        int kc = rem / 4, ct = rem % 4;
        const float* W = W2 + (size_t)l * D * D;
#pragma unroll
        for (int j = 0; j < 8; j++) {
            int k = kc * 32 + kg * 8 + j;
            vals[j] = f2bf(W[k * D + ct * 16 + c]);
        }
        dst = W2P + ((size_t)f3 * 64 + L) * 8;
    }
    i4 v = __builtin_bit_cast(i4, *(bf8*)vals);
    *(i4*)dst = v;
}

// ---------------- MFMA compute ----------------

__global__ __launch_bounds__(BLK) void k_gemm_h(
    const unsigned short* __restrict__ xb, const unsigned short* __restrict__ WgPl,
    unsigned short* __restrict__ h, float* __restrict__ a_s,
    float* __restrict__ a_d, int N)
{
    int r = blockIdx.y;
    int w = threadIdx.x >> 6, L = threadIdx.x & 63;
    int n0 = blockIdx.x * 64 + w * 16;
    int lo = L & 15, kg = L >> 4;
    int nA = n0 + lo; if (nA >= N) nA = N - 1;
    bf8 a0 = ld_frag_g(xb + (size_t)nA * D + kg * 8);
    bf8 a1 = ld_frag_g(xb + (size_t)nA * D + 32 + kg * 8);
    const unsigned short* Wbase = WgPl + (size_t)r * 10 * 512;
#pragma unroll
    for (int ct = 0; ct < 5; ct++) {
        f4 acc = {0.f, 0.f, 0.f, 0.f};
        bf8 b0 = ld_frag_g(Wbase + (size_t)ct * 512 + L * 8);
        bf8 b1 = ld_frag_g(Wbase + (size_t)(5 + ct) * 512 + L * 8);
        acc = __builtin_amdgcn_mfma_f32_16x16x32_bf16(a0, b0, acc, 0, 0, 0);
        acc = __builtin_amdgcn_mfma_f32_16x16x32_bf16(a1, b1, acc, 0, 0, 0);
#pragma unroll
        for (int q = 0; q < 4; q++) {
            int node = n0 + kg * 4 + q;
            if (node < N) {
                if (ct < 4)
                    h[((size_t)r * N + node) * D + ct * 16 + lo] = f2bf(acc[q]);
                else if (lo == 0)
                    a_s[(size_t)r * N + node] = acc[q];
                else if (lo == 1)
                    a_d[(size_t)r * N + node] = acc[q];
            }
        }
    }
}

// GAT aggregation: dual-edge inner loop. Lanes 0-31 = edge A, 32-63 = edge B;
// each lane handles 2 bf16 features via one dword load. LDS pairs hold
// (row byte offset, exp weight); one ds_read_b128 feeds 4 edges.
__global__ __launch_bounds__(BLK) void k_agg(
    const unsigned short* __restrict__ h, const float* __restrict__ a_sall,
    const float* __restrict__ a_dall, const int* __restrict__ prefix,
    const int* __restrict__ srcsall, const float* __restrict__ gatB,
    unsigned short* __restrict__ g, int N, int E)
{
    __shared__ int2 pairs[WPB][64];
    int r = blockIdx.y;
    int w = threadIdx.x >> 6, lane = threadIdx.x & 63;
    int half = lane >> 5, fl = lane & 31;        // features 2*fl, 2*fl+1
    int d = blockIdx.x * WPB + w;
    if (d >= N) d = N - 1;

    const unsigned short* hr = h + (size_t)r * N * D;     // 128-B rows
    const float* a_src = a_sall + (size_t)r * N;
    const int* starts = prefix + (size_t)r * (N + 1);
    const int* srcs = srcsall + (size_t)r * E;

    int base = starts[d];
    int cnt = starts[d + 1] - base;
    float ad = a_dall[(size_t)r * N + d];

    float e_self = __expf(lrelu(a_src[d] + ad));
    float zpart = (lane == 0) ? e_self : 0.f;
    float accx, accy;
    {
        unsigned u = ((const unsigned*)(hr + (size_t)d * D))[fl];
        float flo = __uint_as_float(u << 16);
        float fhi = __uint_as_float(u & 0xffff0000u);
        accx = (half == 0) ? e_self * flo : 0.f;  // self-loop counted in half 0 only
        accy = (half == 0) ? e_self * fhi : 0.f;
    }

    for (int j0 = 0; j0 < cnt; j0 += 64) {
        int jj = j0 + lane;
        bool valid = jj < cnt;
        int s = valid ? srcs[base + jj] : 0;
        float e = valid ? __expf(lrelu(a_src[s] + ad)) : 0.f;
        zpart += e;
        pairs[w][lane] = make_int2(s * (int)(D * 2), __float_as_int(e));
        __threadfence_block();
        int lim = cnt - j0; if (lim > 64) lim = 64;
        int rlim = (lim + 3) & ~3;               // pad edges have e=0
        for (int t4 = 0; t4 < rlim; t4 += 4) {
            i4 pv = *(const i4*)(&pairs[w][t4 + 2 * half]);
            unsigned uA = *(const unsigned*)((const char*)hr + pv.x + fl * 4);
            unsigned uB = *(const unsigned*)((const char*)hr + pv.z + fl * 4);
            float eA = __int_as_float(pv.y), eB = __int_as_float(pv.w);
            accx = fmaf(eA, __uint_as_float(uA << 16), accx);
            accy = fmaf(eA, __uint_as_float(uA & 0xffff0000u), accy);
            accx = fmaf(eB, __uint_as_float(uB << 16), accx);
            accy = fmaf(eB, __uint_as_float(uB & 0xffff0000u), accy);
        }
        __threadfence_block();
    }

    // reduce z across all 64 lanes; fold edge-halves of acc
    float z = zpart;
#pragma unroll
    for (int off = 32; off; off >>= 1) z += __shfl_xor(z, off);
    accx += __shfl_xor(accx, 32);
    accy += __shfl_xor(accy, 32);

    if (half == 0) {
        float rz = 1.f / z;
        float vlo = accx * rz + gatB[r * D + 2 * fl];
        float vhi = accy * rz + gatB[r * D + 2 * fl + 1];
        unsigned o = (unsigned)f2bf(vlo) | ((unsigned)f2bf(vhi) << 16);
        ((unsigned*)g)[((size_t)r * N + d) * 32 + fl] = o;
    }
}

// fused MLP: out = tanh(b1 + [xb|g0..g3] @ W1) @ W2 + b2
__global__ __launch_bounds__(BLK) void k_mlp(
    const unsigned short* __restrict__ xb, const unsigned short* __restrict__ g,
    const unsigned short* __restrict__ W1Pl, const float* __restrict__ b1l,
    const unsigned short* __restrict__ W2Pl, const float* __restrict__ b2l,
    void* __restrict__ outp, int N, int last)
{
    __shared__ unsigned short sh[WPB][16 * 80];
    int w = threadIdx.x >> 6, L = threadIdx.x & 63;
    int n0 = blockIdx.x * 64 + w * 16;
    int lo = L & 15, kg = L >> 4;
    int nA = n0 + lo; if (nA >= N) nA = N - 1;

    f4 acc[4];
#pragma unroll
    for (int ct = 0; ct < 4; ct++) acc[ct] = (f4){0.f, 0.f, 0.f, 0.f};

#pragma unroll
    for (int p = 0; p < 5; p++) {
        const unsigned short* plane = (p == 0) ? xb : g + (size_t)(p - 1) * N * D;
#pragma unroll
        for (int kc2 = 0; kc2 < 2; kc2++) {
            bf8 a = ld_frag_g(plane + (size_t)nA * D + kc2 * 32 + kg * 8);
            int kc = p * 2 + kc2;
#pragma unroll
            for (int ct = 0; ct < 4; ct++) {
                bf8 b = ld_frag_g(W1Pl + ((size_t)(kc * 4 + ct) * 512 + L * 8));
                acc[ct] = __builtin_amdgcn_mfma_f32_16x16x32_bf16(a, b, acc[ct], 0, 0, 0);
            }
        }
    }

    unsigned short* tile = &sh[w][0];
#pragma unroll
    for (int ct = 0; ct < 4; ct++) {
        float bb = b1l[ct * 16 + lo];
#pragma unroll
        for (int q = 0; q < 4; q++)
            tile[(kg * 4 + q) * 80 + ct * 16 + lo] = f2bf(tanhf(acc[ct][q] + bb));
    }
    __syncthreads();

    f4 o[4];
#pragma unroll
    for (int ct = 0; ct < 4; ct++) o[ct] = (f4){0.f, 0.f, 0.f, 0.f};
#pragma unroll
    for (int kc = 0; kc < 2; kc++) {
        const unsigned short* ap = tile + lo * 80 + kc * 32 + kg * 8;
        i4 av = *(const i4*)ap;
        bf8 a = __builtin_bit_cast(bf8, av);
#pragma unroll
        for (int ct = 0; ct < 4; ct++) {
            bf8 b = ld_frag_g(W2Pl + ((size_t)(kc * 4 + ct) * 512 + L * 8));
            o[ct] = __builtin_amdgcn_mfma_f32_16x16x32_bf16(a, b, o[ct], 0, 0, 0);
        }
    }
#pragma unroll
    for (int ct = 0; ct < 4; ct++) {
        float bb = b2l[ct * 16 + lo];
#pragma unroll
        for (int q = 0; q < 4; q++) {
            int node = n0 + kg * 4 + q;
            if (node < N) {
                int col = ct * 16 + lo;
                float v = o[ct][q] + bb;
                if (last) ((float*)outp)[(size_t)node * D + col] = v;
                else ((unsigned short*)outp)[(size_t)node * D + col] = f2bf(v);
            }
        }
    }
}

// ---------------- launch ----------------

extern "C" void kernel_launch(void* const* d_in, const int* in_sizes, int n_in,
                              void* d_out, int out_size, void* d_ws, size_t ws_size,
                              hipStream_t stream)
{
    const float* x    = (const float*)d_in[0];
    const int*   e0   = (const int*)d_in[1];
    const int*   e1   = (const int*)d_in[2];
    const int*   e2   = (const int*)d_in[3];
    const int*   e3   = (const int*)d_in[4];
    const float* gatW = (const float*)d_in[5];
    const float* atS  = (const float*)d_in[6];
    const float* atD  = (const float*)d_in[7];
    const float* gatB = (const float*)d_in[8];
    const float* W1   = (const float*)d_in[9];
    const float* b1   = (const float*)d_in[10];
    const float* W2   = (const float*)d_in[11];
    const float* b2   = (const float*)d_in[12];
    float* out = (float*)d_out;

    const int N = in_sizes[0] / D;
    const int E = in_sizes[1] / 2;
    const int NB = (N + DPB - 1) / DPB;

    size_t off = 0;
    auto alloc = [&](size_t bytes) { size_t o = off; off = (off + bytes + 255) & ~(size_t)255; return o; };
    unsigned short* xb    = (unsigned short*)((char*)d_ws + alloc((size_t)N * D * 2));
    unsigned short* xnext = (unsigned short*)((char*)d_ws + alloc((size_t)N * D * 2));
    unsigned short* h     = (unsigned short*)((char*)d_ws + alloc((size_t)4 * N * D * 2));
    unsigned short* g     = (unsigned short*)((char*)d_ws + alloc((size_t)4 * N * D * 2));
    unsigned* staging = (unsigned*)g;
    float* a_s   = (float*)((char*)d_ws + alloc((size_t)4 * N * 4));
    float* a_d   = (float*)((char*)d_ws + alloc((size_t)4 * N * 4));
    int* prefix  = (int*)((char*)d_ws + alloc((size_t)4 * (N + 1) * 4));
    int* srcs    = (int*)((char*)d_ws + alloc((size_t)4 * E * 4));
    int* bcnt    = (int*)((char*)d_ws + alloc((size_t)4 * NB * 4));
    int* boff    = (int*)((char*)d_ws + alloc((size_t)4 * (NB + 1) * 4));
    int* bcur    = (int*)((char*)d_ws + alloc((size_t)4 * NB * 4));
    unsigned short* WgP = (unsigned short*)((char*)d_ws + alloc((size_t)80 * 512 * 2));
    unsigned short* W1P = (unsigned short*)((char*)d_ws + alloc((size_t)80 * 512 * 2));
    unsigned short* W2P = (unsigned short*)((char*)d_ws + alloc((size_t)16 * 512 * 2));
    (void)ws_size;

    const int partBlocks = (E + CHUNK - 1) / CHUNK;
    const int tileBlocks = (N + 63) / 64;
    const int aggBlocks  = (N + WPB - 1) / WPB;

    k_pack<<<176, 64, 0, stream>>>(gatW, atS, atD, W1, W2, WgP, W1P, W2P);
    k_xcast<<<(N * D / 4 + 255) / 256, 256, 0, stream>>>(x, xb, N * D / 4);

    hipMemsetAsync(bcnt, 0, (size_t)4 * NB * 4, stream);
    k_bcount<<<dim3(partBlocks, 4), 256, 0, stream>>>(e0, e1, e2, e3, bcnt, E, NB);
    k_bscan<<<dim3(1, 4), 1024, 0, stream>>>(bcnt, boff, bcur, prefix, E, N, NB);
    k_part<<<dim3(partBlocks, 4), 256, 0, stream>>>(e0, e1, e2, e3, bcur, staging, E, NB);
    k_place<<<dim3(NB, 4), 256, 0, stream>>>(staging, boff, prefix, srcs, N, E, NB);

    for (int l = 0; l < 2; l++) {
        const unsigned short* xin = (l == 0) ? xb : xnext;
        void* xout = (l == 1) ? (void*)out : (void*)xnext;

        k_gemm_h<<<dim3(tileBlocks, 4), BLK, 0, stream>>>(
            xin, WgP + (size_t)l * 4 * 10 * 512, h, a_s, a_d, N);
        k_agg<<<dim3(aggBlocks, 4), BLK, 0, stream>>>(
            h, a_s, a_d, prefix, srcs, gatB + (size_t)l * 4 * D, g, N, E);
        k_mlp<<<tileBlocks, BLK, 0, stream>>>(
            xin, g, W1P + (size_t)l * 40 * 512, b1 + (size_t)l * D,
            W2P + (size_t)l * 8 * 512, b2 + (size_t)l * D,
            xout, N, l == 1 ? 1 : 0);
    }
}

// Round 6
// 686.032 us; speedup vs baseline: 4.9743x; 1.2303x over previous
//
#include <hip/hip_runtime.h>
#include <hip/hip_bf16.h>
#include <math.h>

#define D 64
#define NEG 0.2f
#define WPB 4
#define BLK 256
#define DPB 128
#define MAXNB 1024
#define CHUNK 16384

typedef __attribute__((ext_vector_type(8))) short bf8;
typedef __attribute__((ext_vector_type(4))) float f4;
typedef __attribute__((ext_vector_type(4))) int i4;

__device__ __forceinline__ float lrelu(float v) { return v > 0.f ? v : NEG * v; }

__device__ __forceinline__ unsigned short f2bf(float f) {
    unsigned u = __float_as_uint(f);
    u = (u + 0x7fffu + ((u >> 16) & 1u)) >> 16;   // RTNE
    return (unsigned short)u;
}
__device__ __forceinline__ bf8 ld_frag_g(const unsigned short* p) {
    i4 v = *(const i4*)p;
    return __builtin_bit_cast(bf8, v);
}

__device__ __forceinline__ const int* edge_ptr(const int* e0, const int* e1,
                                               const int* e2, const int* e3, int r)
{
    return (r == 0) ? e0 : (r == 1) ? e1 : (r == 2) ? e2 : e3;
}

// ---------------- bucketed CSR build ----------------

__global__ __launch_bounds__(256) void k_bcount(
    const int* __restrict__ e0, const int* __restrict__ e1,
    const int* __restrict__ e2, const int* __restrict__ e3,
    int* __restrict__ bcnt, int E, int NB)
{
    int r = blockIdx.y;
    const int* dst = edge_ptr(e0, e1, e2, e3, r) + E;
    __shared__ int hist[MAXNB];
    for (int i = threadIdx.x; i < NB; i += 256) hist[i] = 0;
    __syncthreads();
    int base = blockIdx.x * CHUNK;
    int end = base + CHUNK < E ? base + CHUNK : E;
    for (int i = base + threadIdx.x; i < end; i += 256)
        atomicAdd(&hist[dst[i] >> 7], 1);
    __syncthreads();
    for (int i = threadIdx.x; i < NB; i += 256)
        if (hist[i]) atomicAdd(&bcnt[r * NB + i], hist[i]);
}

__global__ __launch_bounds__(1024) void k_bscan(
    const int* __restrict__ bcnt, int* __restrict__ boff,
    int* __restrict__ bcur, int* __restrict__ prefix, int E, int N, int NB)
{
    int r = blockIdx.y;
    __shared__ int sh[1024];
    int t = threadIdx.x;
    int v = (t < NB) ? bcnt[r * NB + t] : 0;
    sh[t] = v;
    __syncthreads();
    for (int off = 1; off < 1024; off <<= 1) {
        int add = (t >= off) ? sh[t - off] : 0;
        __syncthreads();
        sh[t] += add;
        __syncthreads();
    }
    if (t < NB) {
        int excl = sh[t] - v;
        boff[r * (NB + 1) + t] = excl;
        bcur[r * NB + t] = excl;
    }
    if (t == 0) {
        boff[r * (NB + 1) + NB] = E;
        prefix[(size_t)r * (N + 1) + N] = E;
    }
}

__global__ __launch_bounds__(256) void k_part(
    const int* __restrict__ e0, const int* __restrict__ e1,
    const int* __restrict__ e2, const int* __restrict__ e3,
    int* __restrict__ gcur, unsigned* __restrict__ staging, int E, int NB)
{
    int r = blockIdx.y;
    const int* ep = edge_ptr(e0, e1, e2, e3, r);
    const int* srcp = ep;
    const int* dstp = ep + E;
    __shared__ int hist[MAXNB];
    __shared__ int base[MAXNB];
    for (int j = threadIdx.x; j < NB; j += 256) hist[j] = 0;
    __syncthreads();
    int begin = blockIdx.x * CHUNK;
    int end = begin + CHUNK < E ? begin + CHUNK : E;
    for (int i = begin + threadIdx.x; i < end; i += 256)
        atomicAdd(&hist[dstp[i] >> 7], 1);
    __syncthreads();
    for (int j = threadIdx.x; j < NB; j += 256) {
        int c = hist[j];
        base[j] = c ? atomicAdd(&gcur[r * NB + j], c) : 0;
        hist[j] = 0;
    }
    __syncthreads();
    unsigned* stg = staging + (size_t)r * E;
    for (int i = begin + threadIdx.x; i < end; i += 256) {
        int d = dstp[i];
        int b = d >> 7;
        int pos = base[b] + atomicAdd(&hist[b], 1);
        stg[pos] = ((unsigned)srcp[i] << 7) | (unsigned)(d & 127);
    }
}

__global__ __launch_bounds__(256) void k_place(
    const unsigned* __restrict__ staging, const int* __restrict__ boff,
    int* __restrict__ prefix, int* __restrict__ srcs, int N, int E, int NB)
{
    int r = blockIdx.y;
    int b = blockIdx.x;
    int t = threadIdx.x;
    __shared__ int lcount[DPB];
    __shared__ int ls[DPB];
    __shared__ int lcur[DPB];
    int gbase = boff[r * (NB + 1) + b];
    int bcnt = boff[r * (NB + 1) + b + 1] - gbase;
    if (t < DPB) lcount[t] = 0;
    __syncthreads();
    const unsigned* st = staging + (size_t)r * E + gbase;
    for (int i = t; i < bcnt; i += 256)
        atomicAdd(&lcount[st[i] & 127], 1);
    __syncthreads();
    if (t < DPB) ls[t] = lcount[t];
    __syncthreads();
    for (int off = 1; off < DPB; off <<= 1) {
        int add = (t < DPB && t >= off) ? ls[t - off] : 0;
        __syncthreads();
        if (t < DPB) ls[t] += add;
        __syncthreads();
    }
    int lo = b * DPB;
    if (t < DPB) {
        int excl = ls[t] - lcount[t];
        lcur[t] = excl;
        int d = lo + t;
        if (d < N) prefix[(size_t)r * (N + 1) + d] = gbase + excl;
    }
    __syncthreads();
    for (int i = t; i < bcnt; i += 256) {
        unsigned v = st[i];
        int pos = atomicAdd(&lcur[v & 127], 1);
        srcs[(size_t)r * E + gbase + pos] = (int)(v >> 7);
    }
}

// ---------------- setup: cast + weight packing ----------------

__global__ __launch_bounds__(256) void k_xcast(
    const float* __restrict__ x, unsigned short* __restrict__ xb, int n4)
{
    int i = blockIdx.x * 256 + threadIdx.x;
    if (i < n4) {
        float4 v = ((const float4*)x)[i];
        ushort4 o;
        o.x = f2bf(v.x); o.y = f2bf(v.y); o.z = f2bf(v.z); o.w = f2bf(v.w);
        ((ushort4*)xb)[i] = o;
    }
}

__global__ __launch_bounds__(64) void k_pack(
    const float* __restrict__ gatW, const float* __restrict__ atS,
    const float* __restrict__ atD, const float* __restrict__ W1,
    const float* __restrict__ W2, unsigned short* __restrict__ WgP,
    unsigned short* __restrict__ W1P, unsigned short* __restrict__ W2P)
{
    int f = blockIdx.x;
    int L = threadIdx.x;
    int kg = L >> 4, c = L & 15;
    unsigned short vals[8];
    unsigned short* dst;
    if (f < 80) {
        int m = f / 10, rem = f % 10;
        int l = m / 4, r = m % 4;
        int kc = rem / 5, ct = rem % 5;
        const float* W = gatW + (size_t)(l * 4 + r) * D * D;
        if (ct < 4) {
#pragma unroll
            for (int j = 0; j < 8; j++) {
                int k = kc * 32 + kg * 8 + j;
                vals[j] = f2bf(W[k * D + ct * 16 + c]);
            }
        } else {
            const float* att = (c == 0) ? atS + (size_t)(l * 4 + r) * D
                                        : atD + (size_t)(l * 4 + r) * D;
#pragma unroll
            for (int j = 0; j < 8; j++) {
                int k = kc * 32 + kg * 8 + j;
                float s = 0.f;
                if (c < 2)
                    for (int cc = 0; cc < D; cc++) s += W[k * D + cc] * att[cc];
                vals[j] = f2bf(s);
            }
        }
        dst = WgP + ((size_t)f * 64 + L) * 8;
    } else if (f < 160) {
        int f2 = f - 80;
        int l = f2 / 40, rem = f2 % 40;
        int kc = rem / 4, ct = rem % 4;
        const float* W = W1 + (size_t)l * 5 * D * D;
#pragma unroll
        for (int j = 0; j < 8; j++) {
            int k = kc * 32 + kg * 8 + j;
            vals[j] = f2bf(W[k * D + ct * 16 + c]);
        }
        dst = W1P + ((size_t)f2 * 64 + L) * 8;
    } else {
        int f3 = f - 160;
        int l = f3 / 8, rem = f3 % 8;
        int kc = rem / 4, ct = rem % 4;
        const float* W = W2 + (size_t)l * D * D;
#pragma unroll
        for (int j = 0; j < 8; j++) {
            int k = kc * 32 + kg * 8 + j;
            vals[j] = f2bf(W[k * D + ct * 16 + c]);
        }
        dst = W2P + ((size_t)f3 * 64 + L) * 8;
    }
    i4 v = __builtin_bit_cast(i4, *(bf8*)vals);
    *(i4*)dst = v;
}

// ---------------- MFMA compute ----------------

// shared body: given A-frags for 16 nodes, produce h/a_s/a_d for all 4 relations
__device__ __forceinline__ void gemm_h_body(
    bf8 a0, bf8 a1, const unsigned short* __restrict__ WgPl,
    unsigned short* __restrict__ h, float* __restrict__ a_s,
    float* __restrict__ a_d, int n0, int kg, int lo, int L, int N)
{
#pragma unroll
    for (int r = 0; r < 4; r++) {
        const unsigned short* Wbase = WgPl + (size_t)r * 10 * 512;
#pragma unroll
        for (int ct = 0; ct < 5; ct++) {
            f4 acc = {0.f, 0.f, 0.f, 0.f};
            bf8 b0 = ld_frag_g(Wbase + (size_t)ct * 512 + (size_t)L * 8);
            bf8 b1 = ld_frag_g(Wbase + (size_t)(5 + ct) * 512 + (size_t)L * 8);
            acc = __builtin_amdgcn_mfma_f32_16x16x32_bf16(a0, b0, acc, 0, 0, 0);
            acc = __builtin_amdgcn_mfma_f32_16x16x32_bf16(a1, b1, acc, 0, 0, 0);
#pragma unroll
            for (int q = 0; q < 4; q++) {
                int node = n0 + kg * 4 + q;
                if (node < N) {
                    if (ct < 4)
                        h[((size_t)r * N + node) * D + ct * 16 + lo] = f2bf(acc[q]);
                    else if (lo == 0)
                        a_s[(size_t)r * N + node] = acc[q];
                    else if (lo == 1)
                        a_d[(size_t)r * N + node] = acc[q];
                }
            }
        }
    }
}

// layer-0 gemm: all 4 relations in one dispatch (xb read once)
__global__ __launch_bounds__(BLK) void k_gemm_h(
    const unsigned short* __restrict__ xb, const unsigned short* __restrict__ WgPl,
    unsigned short* __restrict__ h, float* __restrict__ a_s,
    float* __restrict__ a_d, int N)
{
    int w = threadIdx.x >> 6, L = threadIdx.x & 63;
    int n0 = blockIdx.x * 64 + w * 16;
    int lo = L & 15, kg = L >> 4;
    int nA = n0 + lo; if (nA >= N) nA = N - 1;
    bf8 a0 = ld_frag_g(xb + (size_t)nA * D + kg * 8);
    bf8 a1 = ld_frag_g(xb + (size_t)nA * D + 32 + kg * 8);
    gemm_h_body(a0, a1, WgPl, h, a_s, a_d, n0, kg, lo, L, N);
}

// GAT aggregation: 2 dsts per wave (half 0 -> dst 2i, half 1 -> dst 2i+1).
// Each half's 32 lanes cover 64 feats via dword (2 bf16) loads.
__global__ __launch_bounds__(BLK) void k_agg(
    const unsigned short* __restrict__ h, const float* __restrict__ a_sall,
    const float* __restrict__ a_dall, const int* __restrict__ prefix,
    const int* __restrict__ srcsall, const float* __restrict__ gatB,
    unsigned short* __restrict__ g, int N, int E)
{
    __shared__ int2 pairs[WPB][64];
    int r = blockIdx.y;
    int w = threadIdx.x >> 6, lane = threadIdx.x & 63;
    int half = lane >> 5, fl = lane & 31;
    int d = (blockIdx.x * WPB + w) * 2 + half;
    if (d >= N) d = N - 1;

    const unsigned short* hr = h + (size_t)r * N * D;
    const float* a_src = a_sall + (size_t)r * N;
    const int* starts = prefix + (size_t)r * (N + 1);
    const int* srcs = srcsall + (size_t)r * E;

    int base = starts[d];
    int cnt = starts[d + 1] - base;
    float ad = a_dall[(size_t)r * N + d];

    float e_self = __expf(lrelu(a_src[d] + ad));
    float zpart = (fl == 0) ? e_self : 0.f;
    float accx, accy;
    {
        unsigned u = ((const unsigned*)(hr + (size_t)d * D))[fl];
        accx = e_self * __uint_as_float(u << 16);
        accy = e_self * __uint_as_float(u & 0xffff0000u);
    }

    int cntmax = max(cnt, __shfl_xor(cnt, 32));
    for (int c0 = 0; c0 < cntmax; c0 += 32) {
        int jj = c0 + fl;
        bool valid = jj < cnt;
        int s = valid ? srcs[base + jj] : 0;
        float e = valid ? __expf(lrelu(a_src[s] + ad)) : 0.f;
        zpart += e;
        pairs[w][lane] = make_int2(s * (int)(D * 2), __float_as_int(e));
        __threadfence_block();
        int lim = cntmax - c0; if (lim > 32) lim = 32;
        int rlim = (lim + 3) & ~3;               // pad entries have e=0
#pragma unroll 2
        for (int t = 0; t < rlim; t += 2) {
            i4 pv = *(const i4*)(&pairs[w][half * 32 + t]);
            unsigned uA = *(const unsigned*)((const char*)hr + pv.x + fl * 4);
            unsigned uB = *(const unsigned*)((const char*)hr + pv.z + fl * 4);
            float eA = __int_as_float(pv.y), eB = __int_as_float(pv.w);
            accx = fmaf(eA, __uint_as_float(uA << 16), accx);
            accy = fmaf(eA, __uint_as_float(uA & 0xffff0000u), accy);
            accx = fmaf(eB, __uint_as_float(uB << 16), accx);
            accy = fmaf(eB, __uint_as_float(uB & 0xffff0000u), accy);
        }
        __threadfence_block();
    }

    // z-reduce within the 32-lane half
    float z = zpart;
#pragma unroll
    for (int off = 16; off; off >>= 1) z += __shfl_xor(z, off);

    float rz = 1.f / z;
    float vlo = accx * rz + gatB[r * D + 2 * fl];
    float vhi = accy * rz + gatB[r * D + 2 * fl + 1];
    unsigned o = (unsigned)f2bf(vlo) | ((unsigned)f2bf(vhi) << 16);
    ((unsigned*)g)[((size_t)r * N + d) * 32 + fl] = o;
}

// fused MLP: out = tanh(b1 + [xb|g0..g3] @ W1) @ W2 + b2
// If !last: also runs next layer's gemm_h from the in-LDS xout tile.
__global__ __launch_bounds__(BLK) void k_mlp(
    const unsigned short* __restrict__ xb, const unsigned short* __restrict__ g,
    const unsigned short* __restrict__ W1Pl, const float* __restrict__ b1l,
    const unsigned short* __restrict__ W2Pl, const float* __restrict__ b2l,
    void* __restrict__ outp, int N, int last,
    const unsigned short* __restrict__ WgPn, unsigned short* __restrict__ hn,
    float* __restrict__ a_sn, float* __restrict__ a_dn)
{
    __shared__ unsigned short sh[WPB][16 * 80];
    int w = threadIdx.x >> 6, L = threadIdx.x & 63;
    int n0 = blockIdx.x * 64 + w * 16;
    int lo = L & 15, kg = L >> 4;
    int nA = n0 + lo; if (nA >= N) nA = N - 1;

    f4 acc[4];
#pragma unroll
    for (int ct = 0; ct < 4; ct++) acc[ct] = (f4){0.f, 0.f, 0.f, 0.f};

#pragma unroll
    for (int p = 0; p < 5; p++) {
        const unsigned short* plane = (p == 0) ? xb : g + (size_t)(p - 1) * N * D;
#pragma unroll
        for (int kc2 = 0; kc2 < 2; kc2++) {
            bf8 a = ld_frag_g(plane + (size_t)nA * D + kc2 * 32 + kg * 8);
            int kc = p * 2 + kc2;
#pragma unroll
            for (int ct = 0; ct < 4; ct++) {
                bf8 b = ld_frag_g(W1Pl + ((size_t)(kc * 4 + ct) * 512 + (size_t)L * 8));
                acc[ct] = __builtin_amdgcn_mfma_f32_16x16x32_bf16(a, b, acc[ct], 0, 0, 0);
            }
        }
    }

    unsigned short* tile = &sh[w][0];
#pragma unroll
    for (int ct = 0; ct < 4; ct++) {
        float bb = b1l[ct * 16 + lo];
#pragma unroll
        for (int q = 0; q < 4; q++)
            tile[(kg * 4 + q) * 80 + ct * 16 + lo] = f2bf(tanhf(acc[ct][q] + bb));
    }
    __syncthreads();

    f4 o[4];
#pragma unroll
    for (int ct = 0; ct < 4; ct++) o[ct] = (f4){0.f, 0.f, 0.f, 0.f};
#pragma unroll
    for (int kc = 0; kc < 2; kc++) {
        const unsigned short* ap = tile + lo * 80 + kc * 32 + kg * 8;
        i4 av = *(const i4*)ap;
        bf8 a = __builtin_bit_cast(bf8, av);
#pragma unroll
        for (int ct = 0; ct < 4; ct++) {
            bf8 b = ld_frag_g(W2Pl + ((size_t)(kc * 4 + ct) * 512 + (size_t)L * 8));
            o[ct] = __builtin_amdgcn_mfma_f32_16x16x32_bf16(a, b, o[ct], 0, 0, 0);
        }
    }
    __syncthreads();                 // all waves done reading hidden tile
#pragma unroll
    for (int ct = 0; ct < 4; ct++) {
        float bb = b2l[ct * 16 + lo];
#pragma unroll
        for (int q = 0; q < 4; q++) {
            int node = n0 + kg * 4 + q;
            int col = ct * 16 + lo;
            float v = o[ct][q] + bb;
            if (node < N) {
                if (last) ((float*)outp)[(size_t)node * D + col] = v;
                else ((unsigned short*)outp)[(size_t)node * D + col] = f2bf(v);
            }
            if (!last) tile[(kg * 4 + q) * 80 + col] = f2bf(v);
        }
    }
    if (last) return;

    // fused next-layer gemm_h from the xout tile
    __syncthreads();
    bf8 a0, a1;
    {
        i4 v0 = *(const i4*)(tile + lo * 80 + kg * 8);
        i4 v1 = *(const i4*)(tile + lo * 80 + 32 + kg * 8);
        a0 = __builtin_bit_cast(bf8, v0);
        a1 = __builtin_bit_cast(bf8, v1);
    }
    gemm_h_body(a0, a1, WgPn, hn, a_sn, a_dn, n0, kg, lo, L, N);
}

// ---------------- launch ----------------

extern "C" void kernel_launch(void* const* d_in, const int* in_sizes, int n_in,
                              void* d_out, int out_size, void* d_ws, size_t ws_size,
                              hipStream_t stream)
{
    const float* x    = (const float*)d_in[0];
    const int*   e0   = (const int*)d_in[1];
    const int*   e1   = (const int*)d_in[2];
    const int*   e2   = (const int*)d_in[3];
    const int*   e3   = (const int*)d_in[4];
    const float* gatW = (const float*)d_in[5];
    const float* atS  = (const float*)d_in[6];
    const float* atD  = (const float*)d_in[7];
    const float* gatB = (const float*)d_in[8];
    const float* W1   = (const float*)d_in[9];
    const float* b1   = (const float*)d_in[10];
    const float* W2   = (const float*)d_in[11];
    const float* b2   = (const float*)d_in[12];
    float* out = (float*)d_out;

    const int N = in_sizes[0] / D;
    const int E = in_sizes[1] / 2;
    const int NB = (N + DPB - 1) / DPB;

    size_t off = 0;
    auto alloc = [&](size_t bytes) { size_t o = off; off = (off + bytes + 255) & ~(size_t)255; return o; };
    unsigned short* xb    = (unsigned short*)((char*)d_ws + alloc((size_t)N * D * 2));
    unsigned short* xnext = (unsigned short*)((char*)d_ws + alloc((size_t)N * D * 2));
    unsigned short* h     = (unsigned short*)((char*)d_ws + alloc((size_t)4 * N * D * 2));
    unsigned short* g     = (unsigned short*)((char*)d_ws + alloc((size_t)4 * N * D * 2));
    unsigned* staging = (unsigned*)g;        // alias: CSR build precedes g use
    float* a_s   = (float*)((char*)d_ws + alloc((size_t)4 * N * 4));
    float* a_d   = (float*)((char*)d_ws + alloc((size_t)4 * N * 4));
    int* prefix  = (int*)((char*)d_ws + alloc((size_t)4 * (N + 1) * 4));
    int* srcs    = (int*)((char*)d_ws + alloc((size_t)4 * E * 4));
    int* bcnt    = (int*)((char*)d_ws + alloc((size_t)4 * NB * 4));
    int* boff    = (int*)((char*)d_ws + alloc((size_t)4 * (NB + 1) * 4));
    int* bcur    = (int*)((char*)d_ws + alloc((size_t)4 * NB * 4));
    unsigned short* WgP = (unsigned short*)((char*)d_ws + alloc((size_t)80 * 512 * 2));
    unsigned short* W1P = (unsigned short*)((char*)d_ws + alloc((size_t)80 * 512 * 2));
    unsigned short* W2P = (unsigned short*)((char*)d_ws + alloc((size_t)16 * 512 * 2));
    (void)ws_size;

    const int partBlocks = (E + CHUNK - 1) / CHUNK;
    const int tileBlocks = (N + 63) / 64;
    const int aggBlocks  = (N + 8 * 1 - 1) / 8;   // 2 dsts/wave * 4 waves

    k_pack<<<176, 64, 0, stream>>>(gatW, atS, atD, W1, W2, WgP, W1P, W2P);
    k_xcast<<<(N * D / 4 + 255) / 256, 256, 0, stream>>>(x, xb, N * D / 4);

    hipMemsetAsync(bcnt, 0, (size_t)4 * NB * 4, stream);
    k_bcount<<<dim3(partBlocks, 4), 256, 0, stream>>>(e0, e1, e2, e3, bcnt, E, NB);
    k_bscan<<<dim3(1, 4), 1024, 0, stream>>>(bcnt, boff, bcur, prefix, E, N, NB);
    k_part<<<dim3(partBlocks, 4), 256, 0, stream>>>(e0, e1, e2, e3, bcur, staging, E, NB);
    k_place<<<dim3(NB, 4), 256, 0, stream>>>(staging, boff, prefix, srcs, N, E, NB);

    // layer 0
    k_gemm_h<<<tileBlocks, BLK, 0, stream>>>(xb, WgP, h, a_s, a_d, N);
    k_agg<<<dim3(aggBlocks, 4), BLK, 0, stream>>>(
        h, a_s, a_d, prefix, srcs, gatB, g, N, E);
    k_mlp<<<tileBlocks, BLK, 0, stream>>>(
        xb, g, W1P, b1, W2P, b2, xnext, N, 0,
        WgP + (size_t)40 * 512, h, a_s, a_d);   // fused layer-1 gemm_h

    // layer 1
    k_agg<<<dim3(aggBlocks, 4), BLK, 0, stream>>>(
        h, a_s, a_d, prefix, srcs, gatB + (size_t)4 * D, g, N, E);
    k_mlp<<<tileBlocks, BLK, 0, stream>>>(
        xnext, g, W1P + (size_t)40 * 512, b1 + D, W2P + (size_t)8 * 512, b2 + D,
        out, N, 1, nullptr, nullptr, nullptr, nullptr);
}

// Round 7
// 594.497 us; speedup vs baseline: 5.7402x; 1.1540x over previous
//
#include <hip/hip_runtime.h>
#include <hip/hip_bf16.h>
#include <math.h>

#define D 64
#define NEG 0.2f
#define WPB 4
#define BLK 256
#define DPB 128
#define MAXNB 1024
#define CHUNK 16384
#define PCHUNK 8192

typedef __attribute__((ext_vector_type(8))) short bf8;
typedef __attribute__((ext_vector_type(4))) float f4;
typedef __attribute__((ext_vector_type(4))) int i4;

__device__ __forceinline__ float lrelu(float v) { return v > 0.f ? v : NEG * v; }

__device__ __forceinline__ unsigned short f2bf(float f) {
    unsigned u = __float_as_uint(f);
    u = (u + 0x7fffu + ((u >> 16) & 1u)) >> 16;   // RTNE
    return (unsigned short)u;
}
__device__ __forceinline__ bf8 ld_frag_g(const unsigned short* p) {
    i4 v = *(const i4*)p;
    return __builtin_bit_cast(bf8, v);
}

__device__ __forceinline__ const int* edge_ptr(const int* e0, const int* e1,
                                               const int* e2, const int* e3, int r)
{
    return (r == 0) ? e0 : (r == 1) ? e1 : (r == 2) ? e2 : e3;
}

// ---------------- bucketed CSR build ----------------

__global__ __launch_bounds__(256) void k_bcount(
    const int* __restrict__ e0, const int* __restrict__ e1,
    const int* __restrict__ e2, const int* __restrict__ e3,
    int* __restrict__ bcnt, int E, int NB)
{
    int r = blockIdx.y;
    const int* dst = edge_ptr(e0, e1, e2, e3, r) + E;
    __shared__ int hist[MAXNB];
    for (int i = threadIdx.x; i < NB; i += 256) hist[i] = 0;
    __syncthreads();
    int base = blockIdx.x * CHUNK;
    int end = base + CHUNK < E ? base + CHUNK : E;
    for (int i = base + threadIdx.x; i < end; i += 256)
        atomicAdd(&hist[dst[i] >> 7], 1);
    __syncthreads();
    for (int i = threadIdx.x; i < NB; i += 256)
        if (hist[i]) atomicAdd(&bcnt[r * NB + i], hist[i]);
}

__global__ __launch_bounds__(1024) void k_bscan(
    const int* __restrict__ bcnt, int* __restrict__ boff,
    int* __restrict__ bcur, int* __restrict__ prefix, int E, int N, int NB)
{
    int r = blockIdx.y;
    __shared__ int sh[1024];
    int t = threadIdx.x;
    int v = (t < NB) ? bcnt[r * NB + t] : 0;
    sh[t] = v;
    __syncthreads();
    for (int off = 1; off < 1024; off <<= 1) {
        int add = (t >= off) ? sh[t - off] : 0;
        __syncthreads();
        sh[t] += add;
        __syncthreads();
    }
    if (t < NB) {
        int excl = sh[t] - v;
        boff[r * (NB + 1) + t] = excl;
        bcur[r * NB + t] = excl;
    }
    if (t == 0) {
        boff[r * (NB + 1) + NB] = E;
        prefix[(size_t)r * (N + 1) + N] = E;
    }
}

// LDS counting-sort partition: bucket-sort the chunk in LDS, reserve each
// bucket's global run with ONE atomic, stream out in position order
// (consecutive positions -> consecutive addresses within each run).
__global__ __launch_bounds__(256) void k_part(
    const int* __restrict__ e0, const int* __restrict__ e1,
    const int* __restrict__ e2, const int* __restrict__ e3,
    int* __restrict__ gcur, unsigned* __restrict__ staging, int E, int NB)
{
    __shared__ unsigned vals[PCHUNK];          // 32 KB
    __shared__ unsigned short bkt[PCHUNK];     // 16 KB
    __shared__ int hist[MAXNB];                // 4 KB
    __shared__ int sbase[MAXNB];               // 4 KB
    __shared__ int gdelta[MAXNB];              // 4 KB
    __shared__ int ssum[256];                  // 1 KB
    int r = blockIdx.y;
    const int* ep = edge_ptr(e0, e1, e2, e3, r);
    const int* srcp = ep;
    const int* dstp = ep + E;
    int t = threadIdx.x;
    for (int j = t; j < MAXNB; j += 256) hist[j] = 0;
    __syncthreads();
    int begin = blockIdx.x * PCHUNK;
    int end = begin + PCHUNK < E ? begin + PCHUNK : E;
    int cnt = end - begin;
    // pass 1: bucket histogram
    for (int i = begin + t; i < end; i += 256)
        atomicAdd(&hist[dstp[i] >> 7], 1);
    __syncthreads();
    // exclusive scan of hist (4 entries per thread)
    int h0 = hist[t * 4], h1 = hist[t * 4 + 1], h2 = hist[t * 4 + 2], h3 = hist[t * 4 + 3];
    int lsum = h0 + h1 + h2 + h3;
    ssum[t] = lsum;
    __syncthreads();
    for (int off = 1; off < 256; off <<= 1) {
        int a = (t >= off) ? ssum[t - off] : 0;
        __syncthreads();
        ssum[t] += a;
        __syncthreads();
    }
    int ex = ssum[t] - lsum;
    sbase[t * 4] = ex;
    sbase[t * 4 + 1] = ex + h0;
    sbase[t * 4 + 2] = ex + h0 + h1;
    sbase[t * 4 + 3] = ex + h0 + h1 + h2;
    __syncthreads();
    // reserve global runs (one atomic per nonzero bucket)
    for (int j = t; j < NB; j += 256) {
        int c = hist[j];
        int gb = c ? atomicAdd(&gcur[r * NB + j], c) : 0;
        gdelta[j] = gb - sbase[j];
    }
    __syncthreads();
    for (int j = t; j < MAXNB; j += 256) hist[j] = 0;   // reuse as rank counter
    __syncthreads();
    // pass 2: rank & place into LDS (bucket-sorted)
    for (int i = begin + t; i < end; i += 256) {
        int d = dstp[i];
        int s = srcp[i];
        int b = d >> 7;
        int rank = atomicAdd(&hist[b], 1);
        int p = sbase[b] + rank;
        vals[p] = ((unsigned)s << 7) | (unsigned)(d & 127);
        bkt[p] = (unsigned short)b;
    }
    __syncthreads();
    // ordered write-out
    unsigned* stg = staging + (size_t)r * E;
    for (int p = t; p < cnt; p += 256)
        stg[p + gdelta[bkt[p]]] = vals[p];
}

__global__ __launch_bounds__(256) void k_place(
    const unsigned* __restrict__ staging, const int* __restrict__ boff,
    int* __restrict__ prefix, int* __restrict__ srcs, int N, int E, int NB)
{
    int r = blockIdx.y;
    int b = blockIdx.x;
    int t = threadIdx.x;
    __shared__ int lcount[DPB];
    __shared__ int ls[DPB];
    __shared__ int lcur[DPB];
    int gbase = boff[r * (NB + 1) + b];
    int bcnt = boff[r * (NB + 1) + b + 1] - gbase;
    if (t < DPB) lcount[t] = 0;
    __syncthreads();
    const unsigned* st = staging + (size_t)r * E + gbase;
    for (int i = t; i < bcnt; i += 256)
        atomicAdd(&lcount[st[i] & 127], 1);
    __syncthreads();
    if (t < DPB) ls[t] = lcount[t];
    __syncthreads();
    for (int off = 1; off < DPB; off <<= 1) {
        int add = (t < DPB && t >= off) ? ls[t - off] : 0;
        __syncthreads();
        if (t < DPB) ls[t] += add;
        __syncthreads();
    }
    int lo = b * DPB;
    if (t < DPB) {
        int excl = ls[t] - lcount[t];
        lcur[t] = excl;
        int d = lo + t;
        if (d < N) prefix[(size_t)r * (N + 1) + d] = gbase + excl;
    }
    __syncthreads();
    for (int i = t; i < bcnt; i += 256) {
        unsigned v = st[i];
        int pos = atomicAdd(&lcur[v & 127], 1);
        srcs[(size_t)r * E + gbase + pos] = (int)(v >> 7);
    }
}

// ---------------- setup: cast + weight packing ----------------

__global__ __launch_bounds__(256) void k_xcast(
    const float* __restrict__ x, unsigned short* __restrict__ xb, int n4)
{
    int i = blockIdx.x * 256 + threadIdx.x;
    if (i < n4) {
        float4 v = ((const float4*)x)[i];
        ushort4 o;
        o.x = f2bf(v.x); o.y = f2bf(v.y); o.z = f2bf(v.z); o.w = f2bf(v.w);
        ((ushort4*)xb)[i] = o;
    }
}

__global__ __launch_bounds__(64) void k_pack(
    const float* __restrict__ gatW, const float* __restrict__ atS,
    const float* __restrict__ atD, const float* __restrict__ W1,
    const float* __restrict__ W2, unsigned short* __restrict__ WgP,
    unsigned short* __restrict__ W1P, unsigned short* __restrict__ W2P)
{
    int f = blockIdx.x;
    int L = threadIdx.x;
    int kg = L >> 4, c = L & 15;
    unsigned short vals[8];
    unsigned short* dst;
    if (f < 80) {
        int m = f / 10, rem = f % 10;
        int l = m / 4, r = m % 4;
        int kc = rem / 5, ct = rem % 5;
        const float* W = gatW + (size_t)(l * 4 + r) * D * D;
        if (ct < 4) {
#pragma unroll
            for (int j = 0; j < 8; j++) {
                int k = kc * 32 + kg * 8 + j;
                vals[j] = f2bf(W[k * D + ct * 16 + c]);
            }
        } else {
            const float* att = (c == 0) ? atS + (size_t)(l * 4 + r) * D
                                        : atD + (size_t)(l * 4 + r) * D;
#pragma unroll
            for (int j = 0; j < 8; j++) {
                int k = kc * 32 + kg * 8 + j;
                float s = 0.f;
                if (c < 2)
                    for (int cc = 0; cc < D; cc++) s += W[k * D + cc] * att[cc];
                vals[j] = f2bf(s);
            }
        }
        dst = WgP + ((size_t)f * 64 + L) * 8;
    } else if (f < 160) {
        int f2 = f - 80;
        int l = f2 / 40, rem = f2 % 40;
        int kc = rem / 4, ct = rem % 4;
        const float* W = W1 + (size_t)l * 5 * D * D;
#pragma unroll
        for (int j = 0; j < 8; j++) {
            int k = kc * 32 + kg * 8 + j;
            vals[j] = f2bf(W[k * D + ct * 16 + c]);
        }
        dst = W1P + ((size_t)f2 * 64 + L) * 8;
    } else {
        int f3 = f - 160;
        int l = f3 / 8, rem = f3 % 8;
        int kc = rem / 4, ct = rem % 4;
        const float* W = W2 + (size_t)l * D * D;
#pragma unroll
        for (int j = 0; j < 8; j++) {
            int k = kc * 32 + kg * 8 + j;
            vals[j] = f2bf(W[k * D + ct * 16 + c]);
        }
        dst = W2P + ((size_t)f3 * 64 + L) * 8;
    }
    i4 v = __builtin_bit_cast(i4, *(bf8*)vals);
    *(i4*)dst = v;
}

// ---------------- MFMA compute ----------------

__device__ __forceinline__ void gemm_h_body(
    bf8 a0, bf8 a1, const unsigned short* __restrict__ WgPl,
    unsigned short* __restrict__ h, float* __restrict__ a_s,
    float* __restrict__ a_d, int n0, int kg, int lo, int L, int N)
{
#pragma unroll
    for (int r = 0; r < 4; r++) {
        const unsigned short* Wbase = WgPl + (size_t)r * 10 * 512;
#pragma unroll
        for (int ct = 0; ct < 5; ct++) {
            f4 acc = {0.f, 0.f, 0.f, 0.f};
            bf8 b0 = ld_frag_g(Wbase + (size_t)ct * 512 + (size_t)L * 8);
            bf8 b1 = ld_frag_g(Wbase + (size_t)(5 + ct) * 512 + (size_t)L * 8);
            acc = __builtin_amdgcn_mfma_f32_16x16x32_bf16(a0, b0, acc, 0, 0, 0);
            acc = __builtin_amdgcn_mfma_f32_16x16x32_bf16(a1, b1, acc, 0, 0, 0);
#pragma unroll
            for (int q = 0; q < 4; q++) {
                int node = n0 + kg * 4 + q;
                if (node < N) {
                    if (ct < 4)
                        h[((size_t)r * N + node) * D + ct * 16 + lo] = f2bf(acc[q]);
                    else if (lo == 0)
                        a_s[(size_t)r * N + node] = acc[q];
                    else if (lo == 1)
                        a_d[(size_t)r * N + node] = acc[q];
                }
            }
        }
    }
}

__global__ __launch_bounds__(BLK) void k_gemm_h(
    const unsigned short* __restrict__ xb, const unsigned short* __restrict__ WgPl,
    unsigned short* __restrict__ h, float* __restrict__ a_s,
    float* __restrict__ a_d, int N)
{
    int w = threadIdx.x >> 6, L = threadIdx.x & 63;
    int n0 = blockIdx.x * 64 + w * 16;
    int lo = L & 15, kg = L >> 4;
    int nA = n0 + lo; if (nA >= N) nA = N - 1;
    bf8 a0 = ld_frag_g(xb + (size_t)nA * D + kg * 8);
    bf8 a1 = ld_frag_g(xb + (size_t)nA * D + 32 + kg * 8);
    gemm_h_body(a0, a1, WgPl, h, a_s, a_d, n0, kg, lo, L, N);
}

// GAT aggregation: 2 dsts per wave, dword (2-feature) lanes, deep unroll.
__global__ __launch_bounds__(BLK) void k_agg(
    const unsigned short* __restrict__ h, const float* __restrict__ a_sall,
    const float* __restrict__ a_dall, const int* __restrict__ prefix,
    const int* __restrict__ srcsall, const float* __restrict__ gatB,
    unsigned short* __restrict__ g, int N, int E)
{
    __shared__ int2 pairs[WPB][64];
    int r = blockIdx.y;
    int w = threadIdx.x >> 6, lane = threadIdx.x & 63;
    int half = lane >> 5, fl = lane & 31;
    int d = (blockIdx.x * WPB + w) * 2 + half;
    if (d >= N) d = N - 1;

    const unsigned short* hr = h + (size_t)r * N * D;
    const float* a_src = a_sall + (size_t)r * N;
    const int* starts = prefix + (size_t)r * (N + 1);
    const int* srcs = srcsall + (size_t)r * E;

    int base = starts[d];
    int cnt = starts[d + 1] - base;
    float ad = a_dall[(size_t)r * N + d];

    float e_self = __expf(lrelu(a_src[d] + ad));
    float zpart = (fl == 0) ? e_self : 0.f;
    float accx, accy;
    {
        unsigned u = ((const unsigned*)(hr + (size_t)d * D))[fl];
        accx = e_self * __uint_as_float(u << 16);
        accy = e_self * __uint_as_float(u & 0xffff0000u);
    }

    int cntmax = max(cnt, __shfl_xor(cnt, 32));
    for (int c0 = 0; c0 < cntmax; c0 += 32) {
        int jj = c0 + fl;
        bool valid = jj < cnt;
        int s = valid ? srcs[base + jj] : 0;
        float e = valid ? __expf(lrelu(a_src[s] + ad)) : 0.f;
        zpart += e;
        pairs[w][lane] = make_int2(s * (int)(D * 2), __float_as_int(e));
        __threadfence_block();
        int lim = cntmax - c0; if (lim > 32) lim = 32;
        int rlim = (lim + 7) & ~7;               // pad entries have e=0
#pragma unroll 4
        for (int t = 0; t < rlim; t += 2) {
            i4 pv = *(const i4*)(&pairs[w][half * 32 + t]);
            unsigned uA = *(const unsigned*)((const char*)hr + pv.x + fl * 4);
            unsigned uB = *(const unsigned*)((const char*)hr + pv.z + fl * 4);
            float eA = __int_as_float(pv.y), eB = __int_as_float(pv.w);
            accx = fmaf(eA, __uint_as_float(uA << 16), accx);
            accy = fmaf(eA, __uint_as_float(uA & 0xffff0000u), accy);
            accx = fmaf(eB, __uint_as_float(uB << 16), accx);
            accy = fmaf(eB, __uint_as_float(uB & 0xffff0000u), accy);
        }
        __threadfence_block();
    }

    float z = zpart;
#pragma unroll
    for (int off = 16; off; off >>= 1) z += __shfl_xor(z, off);

    float rz = 1.f / z;
    float vlo = accx * rz + gatB[r * D + 2 * fl];
    float vhi = accy * rz + gatB[r * D + 2 * fl + 1];
    unsigned o = (unsigned)f2bf(vlo) | ((unsigned)f2bf(vhi) << 16);
    ((unsigned*)g)[((size_t)r * N + d) * 32 + fl] = o;
}

// fused MLP (+ next-layer gemm_h when !last)
__global__ __launch_bounds__(BLK) void k_mlp(
    const unsigned short* __restrict__ xb, const unsigned short* __restrict__ g,
    const unsigned short* __restrict__ W1Pl, const float* __restrict__ b1l,
    const unsigned short* __restrict__ W2Pl, const float* __restrict__ b2l,
    void* __restrict__ outp, int N, int last,
    const unsigned short* __restrict__ WgPn, unsigned short* __restrict__ hn,
    float* __restrict__ a_sn, float* __restrict__ a_dn)
{
    __shared__ unsigned short sh[WPB][16 * 80];
    int w = threadIdx.x >> 6, L = threadIdx.x & 63;
    int n0 = blockIdx.x * 64 + w * 16;
    int lo = L & 15, kg = L >> 4;
    int nA = n0 + lo; if (nA >= N) nA = N - 1;

    f4 acc[4];
#pragma unroll
    for (int ct = 0; ct < 4; ct++) acc[ct] = (f4){0.f, 0.f, 0.f, 0.f};

#pragma unroll
    for (int p = 0; p < 5; p++) {
        const unsigned short* plane = (p == 0) ? xb : g + (size_t)(p - 1) * N * D;
#pragma unroll
        for (int kc2 = 0; kc2 < 2; kc2++) {
            bf8 a = ld_frag_g(plane + (size_t)nA * D + kc2 * 32 + kg * 8);
            int kc = p * 2 + kc2;
#pragma unroll
            for (int ct = 0; ct < 4; ct++) {
                bf8 b = ld_frag_g(W1Pl + ((size_t)(kc * 4 + ct) * 512 + (size_t)L * 8));
                acc[ct] = __builtin_amdgcn_mfma_f32_16x16x32_bf16(a, b, acc[ct], 0, 0, 0);
            }
        }
    }

    unsigned short* tile = &sh[w][0];
#pragma unroll
    for (int ct = 0; ct < 4; ct++) {
        float bb = b1l[ct * 16 + lo];
#pragma unroll
        for (int q = 0; q < 4; q++)
            tile[(kg * 4 + q) * 80 + ct * 16 + lo] = f2bf(tanhf(acc[ct][q] + bb));
    }
    __syncthreads();

    f4 o[4];
#pragma unroll
    for (int ct = 0; ct < 4; ct++) o[ct] = (f4){0.f, 0.f, 0.f, 0.f};
#pragma unroll
    for (int kc = 0; kc < 2; kc++) {
        const unsigned short* ap = tile + lo * 80 + kc * 32 + kg * 8;
        i4 av = *(const i4*)ap;
        bf8 a = __builtin_bit_cast(bf8, av);
#pragma unroll
        for (int ct = 0; ct < 4; ct++) {
            bf8 b = ld_frag_g(W2Pl + ((size_t)(kc * 4 + ct) * 512 + (size_t)L * 8));
            o[ct] = __builtin_amdgcn_mfma_f32_16x16x32_bf16(a, b, o[ct], 0, 0, 0);
        }
    }
    __syncthreads();
#pragma unroll
    for (int ct = 0; ct < 4; ct++) {
        float bb = b2l[ct * 16 + lo];
#pragma unroll
        for (int q = 0; q < 4; q++) {
            int node = n0 + kg * 4 + q;
            int col = ct * 16 + lo;
            float v = o[ct][q] + bb;
            if (node < N) {
                if (last) ((float*)outp)[(size_t)node * D + col] = v;
                else ((unsigned short*)outp)[(size_t)node * D + col] = f2bf(v);
            }
            if (!last) tile[(kg * 4 + q) * 80 + col] = f2bf(v);
        }
    }
    if (last) return;

    __syncthreads();
    bf8 a0, a1;
    {
        i4 v0 = *(const i4*)(tile + lo * 80 + kg * 8);
        i4 v1 = *(const i4*)(tile + lo * 80 + 32 + kg * 8);
        a0 = __builtin_bit_cast(bf8, v0);
        a1 = __builtin_bit_cast(bf8, v1);
    }
    gemm_h_body(a0, a1, WgPn, hn, a_sn, a_dn, n0, kg, lo, L, N);
}

// ---------------- launch ----------------

extern "C" void kernel_launch(void* const* d_in, const int* in_sizes, int n_in,
                              void* d_out, int out_size, void* d_ws, size_t ws_size,
                              hipStream_t stream)
{
    const float* x    = (const float*)d_in[0];
    const int*   e0   = (const int*)d_in[1];
    const int*   e1   = (const int*)d_in[2];
    const int*   e2   = (const int*)d_in[3];
    const int*   e3   = (const int*)d_in[4];
    const float* gatW = (const float*)d_in[5];
    const float* atS  = (const float*)d_in[6];
    const float* atD  = (const float*)d_in[7];
    const float* gatB = (const float*)d_in[8];
    const float* W1   = (const float*)d_in[9];
    const float* b1   = (const float*)d_in[10];
    const float* W2   = (const float*)d_in[11];
    const float* b2   = (const float*)d_in[12];
    float* out = (float*)d_out;

    const int N = in_sizes[0] / D;
    const int E = in_sizes[1] / 2;
    const int NB = (N + DPB - 1) / DPB;

    size_t off = 0;
    auto alloc = [&](size_t bytes) { size_t o = off; off = (off + bytes + 255) & ~(size_t)255; return o; };
    unsigned short* xb    = (unsigned short*)((char*)d_ws + alloc((size_t)N * D * 2));
    unsigned short* xnext = (unsigned short*)((char*)d_ws + alloc((size_t)N * D * 2));
    unsigned short* h     = (unsigned short*)((char*)d_ws + alloc((size_t)4 * N * D * 2));
    unsigned short* g     = (unsigned short*)((char*)d_ws + alloc((size_t)4 * N * D * 2));
    unsigned* staging = (unsigned*)g;        // alias: CSR build precedes g use
    float* a_s   = (float*)((char*)d_ws + alloc((size_t)4 * N * 4));
    float* a_d   = (float*)((char*)d_ws + alloc((size_t)4 * N * 4));
    int* prefix  = (int*)((char*)d_ws + alloc((size_t)4 * (N + 1) * 4));
    int* srcs    = (int*)((char*)d_ws + alloc((size_t)4 * E * 4));
    int* bcnt    = (int*)((char*)d_ws + alloc((size_t)4 * NB * 4));
    int* boff    = (int*)((char*)d_ws + alloc((size_t)4 * (NB + 1) * 4));
    int* bcur    = (int*)((char*)d_ws + alloc((size_t)4 * NB * 4));
    unsigned short* WgP = (unsigned short*)((char*)d_ws + alloc((size_t)80 * 512 * 2));
    unsigned short* W1P = (unsigned short*)((char*)d_ws + alloc((size_t)80 * 512 * 2));
    unsigned short* W2P = (unsigned short*)((char*)d_ws + alloc((size_t)16 * 512 * 2));
    (void)ws_size;

    const int cntBlocks  = (E + CHUNK - 1) / CHUNK;
    const int partBlocks = (E + PCHUNK - 1) / PCHUNK;
    const int tileBlocks = (N + 63) / 64;
    const int aggBlocks  = (N + 7) / 8;   // 2 dsts/wave * 4 waves

    k_pack<<<176, 64, 0, stream>>>(gatW, atS, atD, W1, W2, WgP, W1P, W2P);
    k_xcast<<<(N * D / 4 + 255) / 256, 256, 0, stream>>>(x, xb, N * D / 4);

    hipMemsetAsync(bcnt, 0, (size_t)4 * NB * 4, stream);
    k_bcount<<<dim3(cntBlocks, 4), 256, 0, stream>>>(e0, e1, e2, e3, bcnt, E, NB);
    k_bscan<<<dim3(1, 4), 1024, 0, stream>>>(bcnt, boff, bcur, prefix, E, N, NB);
    k_part<<<dim3(partBlocks, 4), 256, 0, stream>>>(e0, e1, e2, e3, bcur, staging, E, NB);
    k_place<<<dim3(NB, 4), 256, 0, stream>>>(staging, boff, prefix, srcs, N, E, NB);

    // layer 0
    k_gemm_h<<<tileBlocks, BLK, 0, stream>>>(xb, WgP, h, a_s, a_d, N);
    k_agg<<<dim3(aggBlocks, 4), BLK, 0, stream>>>(
        h, a_s, a_d, prefix, srcs, gatB, g, N, E);
    k_mlp<<<tileBlocks, BLK, 0, stream>>>(
        xb, g, W1P, b1, W2P, b2, xnext, N, 0,
        WgP + (size_t)40 * 512, h, a_s, a_d);   // fused layer-1 gemm_h

    // layer 1
    k_agg<<<dim3(aggBlocks, 4), BLK, 0, stream>>>(
        h, a_s, a_d, prefix, srcs, gatB + (size_t)4 * D, g, N, E);
    k_mlp<<<tileBlocks, BLK, 0, stream>>>(
        xnext, g, W1P + (size_t)40 * 512, b1 + D, W2P + (size_t)8 * 512, b2 + D,
        out, N, 1, nullptr, nullptr, nullptr, nullptr);
}